// Round 1
// 202.312 us; speedup vs baseline: 1.0223x; 1.0223x over previous
//
#include <hip/hip_runtime.h>

#define Nn 100000
#define Tt 16
#define Dd 8
#define Hh 40
#define HP1 41

// ---- workspace layout (float slots) ----
#define CSZ 53248                 // 52*16*64 floats per chunk-partial
#define KCMAX 125                 // 125 chunks * 800 n = 100000 exactly
#define XE_PAIR_OFF 0
#define XE_PAIR_SZ  (Nn * 64)     // dwords: f16 hi (low16) | f16 lo (high16)
#define PART_OFF    (XE_PAIR_OFF + XE_PAIR_SZ)
#define PART_SZ     (16 * CSZ)
#define P_OFF       (PART_OFF + PART_SZ)

// output offsets (flat, return order)
#define OFF_BG1   0
#define OFF_BG2   16
#define OFF_MU    32
#define OFF_KAPPA 160
#define OFF_NU    176
#define OFF_PSI   192
#define OFF_WM    1216
#define OFF_WS    1872
#define OFF_ZA    28768
#define OFF_ZB    28784
#define OFF_EA    28800
#define OFF_EB    28816

typedef _Float16 f16x8 __attribute__((ext_vector_type(8)));
typedef float f32x4 __attribute__((ext_vector_type(4)));
typedef unsigned short u16x8 __attribute__((ext_vector_type(8)));

// A-index into a chunk partial / part16 group: value A[t][i][j]
#define AIDX(i, t, j) ((((i) * 16 + (t)) * 64) + (j))

// ---------------- Kernel 0: ELM expansion -> packed f16-pair Xe [n][64] ----------------
// col layout: [h0..h39, 1, x0..x7, y, 0...0]  (cols 50..63 zero)
__global__ __launch_bounds__(256)
void elm_expand(const float* __restrict__ Xd, const float* __restrict__ Yd,
                const float* __restrict__ W, const float* __restrict__ bb,
                unsigned int* __restrict__ XePair)
{
  __shared__ float sW[Dd * Hh];
  __shared__ float sb[Hh];
  __shared__ float xs[64][9];      // stride 9: conflict-benign
  __shared__ float ys[64];
  __shared__ float hrow[64][41];   // stride 41 (odd): conflict-free col reads
  int tid = threadIdx.x;
  int n0 = blockIdx.x * 64;

  for (int i = tid; i < Dd * Hh; i += 256) sW[i] = W[i];
  if (tid < Hh) sb[tid] = bb[tid];
  if (tid < 128) {
    int nl = tid >> 1, h4 = (tid & 1) * 4;
    int gn = n0 + nl;
    float4 v = (gn < Nn) ? *(const float4*)(Xd + (size_t)gn * 8 + h4)
                         : make_float4(0.f, 0.f, 0.f, 0.f);
    xs[nl][h4 + 0] = v.x; xs[nl][h4 + 1] = v.y;
    xs[nl][h4 + 2] = v.z; xs[nl][h4 + 3] = v.w;
  }
  if (tid < 64) { int gn = n0 + tid; ys[tid] = (gn < Nn) ? Yd[gn] : 0.f; }
  __syncthreads();

  // sigmoids: thread -> (n, 10 h's)
  {
    int nl = tid >> 2, hq = (tid & 3) * 10;
    for (int hh = 0; hh < 10; ++hh) {
      int h = hq + hh;
      float z = sb[h];
#pragma unroll
      for (int d = 0; d < 8; ++d) z = fmaf(xs[nl][d], sW[d * Hh + h], z);
      hrow[nl][h] = 1.f / (1.f + __expf(-z));
    }
  }
  __syncthreads();

  // packed pair store, row-major coalesced
  for (int pass = 0; pass < 16; ++pass) {
    int idx = pass * 256 + tid;
    int nl = idx >> 6, cc = idx & 63;
    int gn = n0 + nl;
    if (gn < Nn) {
      float v = (cc < Hh) ? hrow[nl][cc]
              : (cc == 40) ? 1.f
              : (cc < 49) ? xs[nl][cc - 41]
              : (cc == 49) ? ys[nl] : 0.f;
      _Float16 hi = (_Float16)v;
      _Float16 lo = (_Float16)(v - (float)hi);
      unsigned int u = ((unsigned int)__builtin_bit_cast(unsigned short, lo) << 16)
                     |  (unsigned int)__builtin_bit_cast(unsigned short, hi);
      XePair[(size_t)gn * 64 + cc] = u;
    }
  }
}

// ---------------- Kernel 1: MFMA Gram, split-K, no LDS / no barriers ----------------
// M = i*16 + t (M-tile = one i, rows = t), N = j (4 tiles of 16), K = n.
// 2-term f16 split: value = hi + lo; products hi*hi + hi*lo + lo*hi.
// k-mapping: my-k = (lane>>4)*8 + e, identical for A and B -> permutation-safe.
__device__ __forceinline__ float pair_to_f32(unsigned int u) {
  _Float16 hi = __builtin_bit_cast(_Float16, (unsigned short)(u & 0xffffu));
  _Float16 lo = __builtin_bit_cast(_Float16, (unsigned short)(u >> 16));
  return (float)hi + (float)lo;
}

__global__ __launch_bounds__(256, 2)
void gram_mfma(const float* __restrict__ Phi, const unsigned int* __restrict__ XePair,
               float* __restrict__ P, int CH)
{
  int tid = threadIdx.x;
  int lane = tid & 63;
  int wave = tid >> 6;
  int wg_n = wave & 1;            // N half: tiles {2*wg_n, 2*wg_n+1}
  int wg_m = wave >> 1;           // M half: 7 tiles (wg_m=1: 7th is pad, discarded)
  int l15 = lane & 15, lg = lane >> 4;
  int bM = blockIdx.x;            // 0..3 -> i range [13*bM, 13*bM+13)
  int c  = blockIdx.y;            // K chunk
  int n0 = c * CH;
  int nEnd = n0 + CH; if (nEnd > Nn) nEnd = Nn;   // always a multiple of 32
  int i0 = bM * 13 + wg_m * 7;
  int jB = wg_n * 32 + l15;

  f32x4 acc[7][2];
#pragma unroll
  for (int m = 0; m < 7; ++m) {
    acc[m][0] = (f32x4){0.f, 0.f, 0.f, 0.f};
    acc[m][1] = (f32x4){0.f, 0.f, 0.f, 0.f};
  }

  for (int nb = n0; nb < nEnd; nb += 32) {
    int kb = nb + lg * 8;         // this lane's k-base (my-k = kb + e)

    // phi[k][t] for t = l15 (A rows)
    float ph[8];
#pragma unroll
    for (int e = 0; e < 8; ++e) ph[e] = Phi[(size_t)(kb + e) * 16 + l15];

    // B fragments: xe[k][j] split halves, j = l15 + 16*ntile
    f16x8 bh[2], bl[2];
#pragma unroll
    for (int nt = 0; nt < 2; ++nt) {
      u16x8 vh, vl;
#pragma unroll
      for (int e = 0; e < 8; ++e) {
        unsigned int u = XePair[(size_t)(kb + e) * 64 + jB + nt * 16];
        vh[e] = (unsigned short)(u & 0xffffu);
        vl[e] = (unsigned short)(u >> 16);
      }
      bh[nt] = __builtin_bit_cast(f16x8, vh);
      bl[nt] = __builtin_bit_cast(f16x8, vl);
    }

    // Per M-tile: build A = split(phi * xe_i), then 6 MFMAs
#pragma unroll
    for (int mt = 0; mt < 7; ++mt) {
      int iA = i0 + mt;           // <= 52; col 52..63 of XePair are exact zeros
      f16x8 ah, al;
#pragma unroll
      for (int e = 0; e < 8; ++e) {
        unsigned int u = XePair[(size_t)(kb + e) * 64 + iA];  // 16-way broadcast
        float a = ph[e] * pair_to_f32(u);
        _Float16 h = (_Float16)a;
        ah[e] = h;
        al[e] = (_Float16)(a - (float)h);
      }
#pragma unroll
      for (int nt = 0; nt < 2; ++nt) {
        acc[mt][nt] = __builtin_amdgcn_mfma_f32_16x16x32_f16(ah, bh[nt], acc[mt][nt], 0, 0, 0);
        acc[mt][nt] = __builtin_amdgcn_mfma_f32_16x16x32_f16(ah, bl[nt], acc[mt][nt], 0, 0, 0);
        acc[mt][nt] = __builtin_amdgcn_mfma_f32_16x16x32_f16(al, bh[nt], acc[mt][nt], 0, 0, 0);
      }
    }
  }

  // epilogue: C row = t = lg*4 + r (verified C map), col = j
  int ntile = (wg_m == 1) ? 6 : 7;
  float* Pc = P + (size_t)c * CSZ;
#pragma unroll
  for (int mt = 0; mt < 7; ++mt) {
    if (mt >= ntile) break;
    int iA = i0 + mt;
#pragma unroll
    for (int nt = 0; nt < 2; ++nt) {
      int j = wg_n * 32 + nt * 16 + l15;
#pragma unroll
      for (int r = 0; r < 4; ++r) {
        Pc[(iA * 16 + (lg * 4 + r)) * 64 + j] = acc[mt][nt][r];
      }
    }
  }
}

// ---------------- Kernel 2: chunk-partial reduction (KCe -> 16 groups) ----------------
__global__ __launch_bounds__(256)
void reduce_chunks(const float4* __restrict__ P4, int nchunks, float4* __restrict__ part4)
{
  int g = blockIdx.y;                               // 0..15
  int idx = blockIdx.x * 256 + threadIdx.x;         // 52 blocks cover CSZ/4 = 13312
  int per = (nchunks + 15) / 16;
  int c0 = g * per;
  int c1 = c0 + per; if (c1 > nchunks) c1 = nchunks;
  float4 s = make_float4(0.f, 0.f, 0.f, 0.f);
  for (int cc = c0; cc < c1; ++cc) {
    float4 v = P4[(size_t)cc * (CSZ / 4) + idx];
    s.x += v.x; s.y += v.y; s.z += v.z; s.w += v.w;
  }
  part4[(size_t)g * (CSZ / 4) + idx] = s;
}

// ---------------- Kernel 3: finalize (GJ inverse etc.); sums the 16 partials inline ---
__device__ __forceinline__ float accv(const float* __restrict__ part, int idx) {
  float s = 0.f;
#pragma unroll
  for (int g = 0; g < 16; ++g) s += part[g * CSZ + idx];
  return s;
}

__global__ __launch_bounds__(256)
void finalize_kernel(const float* __restrict__ part, const float* __restrict__ epsA,
                     const float* __restrict__ epsB, const float* __restrict__ zetA,
                     const float* __restrict__ zetB, float* __restrict__ out)
{
  int t = blockIdx.x;
  int tid = threadIdx.x;
  __shared__ float G[HP1][84];          // [M | I] augmented
  __shared__ float As[HP1][HP1 + 1];
  __shared__ float bs[HP1];
  __shared__ float colk[HP1];
  __shared__ float red[256];
  __shared__ float wmv[HP1];
  __shared__ float rowv[4][HP1 + 1];    // per-row partials: wb, wn, trc, quad
  __shared__ float mus[Dd];

  float epsExp = epsA[t] / epsB[t];
  float zetaExp = zetA[t] / zetB[t];

  for (int idx = tid; idx < HP1 * HP1; idx += 256) {
    int i = idx / HP1, j = idx % HP1;
    float a = accv(part, AIDX(i, t, j));
    As[i][j] = a;
    G[i][j] = epsExp * a + (i == j ? zetaExp : 0.f);
    G[i][41 + j] = (i == j) ? 1.f : 0.f;
  }
  for (int idx = tid; idx < HP1; idx += 256) {
    G[idx][82] = 0.f; G[idx][83] = 0.f;
    bs[idx] = accv(part, AIDX(idx, t, 49));
  }
  __syncthreads();

  // column-per-thread decode: c = col offset, ig = 7-row group (ig<6 active)
  int c = tid % HP1;         // 0..40
  int ig = tid / HP1;        // 0..6; use ig<6 (threads 0..245)
  int irow0 = ig * 7;

  // compact Gauss-Jordan: 2 barriers / pivot
  for (int k = 0; k < HP1; ++k) {
    float pivinv = 1.f / G[k][k];
    if (tid >= 1 && tid <= HP1) G[k][k + tid] *= pivinv;
    if (tid < HP1) colk[tid] = (tid == k) ? 0.f : G[tid][k];
    __syncthreads();
    if (ig < 6) {
      int j = k + 1 + c;
      float pk = G[k][j];
#pragma unroll
      for (int r = 0; r < 7; ++r) {
        int i = irow0 + r;
        if (i < HP1 && i != k) G[i][j] = fmaf(-colk[i], pk, G[i][j]);
      }
    }
    __syncthreads();
  }

  // write WS (inverse at cols 41..81)
  for (int idx = tid; idx < HP1 * HP1; idx += 256) {
    int i = idx / HP1, j = idx % HP1;
    out[OFF_WS + (t * HP1 + i) * HP1 + j] = G[i][41 + j];
  }
  // WMv = zetaExp * WS @ b
  if (tid < HP1) {
    float s = 0.f;
    for (int j = 0; j < HP1; ++j) s += G[tid][41 + j] * bs[j];
    float w = zetaExp * s;
    wmv[tid] = w;
    out[OFF_WM + t * HP1 + tid] = w;
  }
  __syncthreads();
  // t2 = sum_ij A_ij WS_ij
  float lt2 = 0.f;
  for (int idx = tid; idx < HP1 * HP1; idx += 256) {
    int i = idx / HP1, j = idx % HP1;
    lt2 += As[i][j] * G[i][41 + j];
  }
  red[tid] = lt2; __syncthreads();
  for (int s = 128; s > 0; s >>= 1) {
    if (tid < s) red[tid] += red[tid + s];
    __syncthreads();
  }
  float t2v = red[0];
  if (tid < HP1) {
    float w = wmv[tid];
    float aw = 0.f;
    for (int j = 0; j < HP1; ++j) aw += As[tid][j] * wmv[j];
    rowv[0][tid] = w * bs[tid];
    rowv[1][tid] = w * w;
    rowv[2][tid] = G[tid][41 + tid];
    rowv[3][tid] = w * aw;
  }
  __syncthreads();

  float sp = accv(part, AIDX(40, t, 40));    // sumPhi[t]
  float kap = 1000.f + sp;
  float syy = accv(part, AIDX(49, t, 49));   // sum phi y^2

  if (tid == 0) {
    float wb = 0.f, wn = 0.f, trc = 0.f, quad = 0.f;
    for (int i = 0; i < HP1; ++i) {
      wb += rowv[0][i]; wn += rowv[1][i]; trc += rowv[2][i]; quad += rowv[3][i];
    }
    float t1 = syy - 2.f * wb + quad;
    out[OFF_BG1 + t] = 1.f + sp;
    float rest = 0.f;
    for (int u = t + 1; u < Tt; ++u) rest += accv(part, AIDX(40, u, 40));
    out[OFF_BG2 + t] = 1.f + rest;            // ALPHA_DP = 1
    out[OFF_KAPPA + t] = kap;
    out[OFF_NU + t] = sp + 100.f;             // sumPhi + NU0
    out[OFF_ZA + t] = zetA[t] + 0.5f * (float)HP1;
    out[OFF_ZB + t] = zetB[t] + 0.5f * (wn + trc);
    out[OFF_EA + t] = epsA[t] + 0.5f * sp;
    out[OFF_EB + t] = epsB[t] + 0.5f * (t1 + t2v);
  }
  // mu
  if (tid < Dd) {
    float m = accv(part, AIDX(40, t, 41 + tid)) / kap;
    mus[tid] = m;
    out[OFF_MU + tid * Tt + t] = m;
  }
  __syncthreads();
  // psi = 500*I + S - kappa * mu mu^T
  if (tid < Dd * Dd) {
    int i = tid / Dd, j = tid % Dd;
    float S = accv(part, AIDX(41 + i, t, 41 + j));
    float v = (i == j ? 500.f : 0.f) + S - kap * mus[i] * mus[j];
    out[OFF_PSI + (i * Dd + j) * Tt + t] = v;
  }
}

extern "C" void kernel_launch(void* const* d_in, const int* in_sizes, int n_in,
                              void* d_out, int out_size, void* d_ws, size_t ws_size,
                              hipStream_t stream) {
  const float* Phi = (const float*)d_in[1];
  const float* Xd  = (const float*)d_in[2];
  const float* Yd  = (const float*)d_in[3];
  const float* W   = (const float*)d_in[4];
  const float* bb  = (const float*)d_in[5];
  const float* eA  = (const float*)d_in[6];
  const float* eB  = (const float*)d_in[7];
  const float* zA  = (const float*)d_in[8];
  const float* zB  = (const float*)d_in[9];
  float* out = (float*)d_out;
  float* ws  = (float*)d_ws;

  unsigned int* XePair = (unsigned int*)(ws + XE_PAIR_OFF);
  float* part = ws + PART_OFF;
  float* P    = ws + P_OFF;

  // adapt chunk count to workspace (deterministic, graph-safe)
  long maxChunks = ((long)(ws_size / 4) - (long)P_OFF) / CSZ;
  int mch = 1;
  while (mch < KCMAX && (long)((KCMAX + mch - 1) / mch) > maxChunks) ++mch;
  int CH = 800 * mch;                  // multiple of 800 -> no k-loop tails
  int KCe = (Nn + CH - 1) / CH;        // = 125 when ws >= ~56 MB (proven available)

  hipLaunchKernelGGL(elm_expand, dim3((Nn + 63) / 64), dim3(256), 0, stream,
                     Xd, Yd, W, bb, XePair);
  hipLaunchKernelGGL(gram_mfma, dim3(4, KCe), dim3(256), 0, stream,
                     Phi, XePair, P, CH);
  hipLaunchKernelGGL(reduce_chunks, dim3(52, 16), dim3(256), 0, stream,
                     (const float4*)P, KCe, (float4*)part);
  hipLaunchKernelGGL(finalize_kernel, dim3(Tt), dim3(256), 0, stream,
                     part, eA, eB, zA, zB, out);
}

// Round 2
// 185.988 us; speedup vs baseline: 1.1121x; 1.0878x over previous
//
#include <hip/hip_runtime.h>

#define Nn 100000
#define Tt 16
#define Dd 8
#define Hh 40
#define HP1 41

// ---- workspace layout (float/dword slots) ----
#define CSZ 53248                  // 52*16*64 floats per chunk-partial
#define XET_OFF  0                 // XeT [64][Nn] pair-dwords (hi f16 | lo f16<<16)
#define XET_SZ   (64 * Nn)
#define PHIT_OFF (XET_OFF + XET_SZ)        // PhiT [16][Nn] f32
#define PHIT_SZ  (16 * Nn)
#define ACC_OFF  (PHIT_OFF + PHIT_SZ)      // reduced acc, CSZ floats
#define PART_OFF (ACC_OFF + CSZ)           // 8 * CSZ partials
#define P_OFF    (PART_OFF + 8 * CSZ)      // chunk partials

// output offsets (flat, return order)
#define OFF_BG1   0
#define OFF_BG2   16
#define OFF_MU    32
#define OFF_KAPPA 160
#define OFF_NU    176
#define OFF_PSI   192
#define OFF_WM    1216
#define OFF_WS    1872
#define OFF_ZA    28768
#define OFF_ZB    28784
#define OFF_EA    28800
#define OFF_EB    28816

typedef _Float16 f16x8 __attribute__((ext_vector_type(8)));
typedef float f32x4 __attribute__((ext_vector_type(4)));
typedef unsigned short u16x8 __attribute__((ext_vector_type(8)));
typedef unsigned int u32x4 __attribute__((ext_vector_type(4)));

// A-index into acc/partials: value A[t][i][j] at ((i*16+t)*64)+j
#define AIDX(i, t, j) ((((i) * 16 + (t)) * 64) + (j))

// ---------------- Kernel 0: ELM expansion -> transposed XeT (f16 pair) + PhiT ------
// Xe col layout c: [h0..h39, 1, x0..x7, y, 0...0] (c=50..63 zero)
__global__ __launch_bounds__(256)
void elm_expand(const float* __restrict__ Phi, const float* __restrict__ Xd,
                const float* __restrict__ Yd, const float* __restrict__ W,
                const float* __restrict__ bb, unsigned int* __restrict__ XeT,
                float* __restrict__ PhiT)
{
  __shared__ float sW[Dd * Hh];
  __shared__ float sb[Hh];
  __shared__ float xs[64][9];
  __shared__ float ys[64];
  __shared__ float hrow[64][41];
  __shared__ float pt[16][68];
  int tid = threadIdx.x;
  int n0 = blockIdx.x * 64;

  for (int i = tid; i < Dd * Hh; i += 256) sW[i] = W[i];
  if (tid < Hh) sb[tid] = bb[tid];
  if (tid < 128) {
    int nl = tid >> 1, h4 = (tid & 1) * 4;
    int gn = n0 + nl;
    float4 v = (gn < Nn) ? *(const float4*)(Xd + (size_t)gn * 8 + h4)
                         : make_float4(0.f, 0.f, 0.f, 0.f);
    xs[nl][h4 + 0] = v.x; xs[nl][h4 + 1] = v.y;
    xs[nl][h4 + 2] = v.z; xs[nl][h4 + 3] = v.w;
  }
  if (tid < 64) { int gn = n0 + tid; ys[tid] = (gn < Nn) ? Yd[gn] : 0.f; }
  {
    int nl = tid >> 2, q = tid & 3;
    int gn = n0 + nl;
    float4 v = (gn < Nn) ? *(const float4*)(Phi + (size_t)gn * 16 + q * 4)
                         : make_float4(0.f, 0.f, 0.f, 0.f);
    pt[q * 4 + 0][nl] = v.x; pt[q * 4 + 1][nl] = v.y;
    pt[q * 4 + 2][nl] = v.z; pt[q * 4 + 3][nl] = v.w;
  }
  __syncthreads();
  // sigmoids: thread -> (n, 10 h's)
  {
    int nl = tid >> 2, hq = (tid & 3) * 10;
    for (int hh = 0; hh < 10; ++hh) {
      int h = hq + hh;
      float z = sb[h];
#pragma unroll
      for (int d = 0; d < 8; ++d) z = fmaf(xs[nl][d], sW[d * Hh + h], z);
      hrow[nl][h] = 1.f / (1.f + __expf(-z));
    }
  }
  __syncthreads();
  // PhiT write: thread (t = tid&15, nq = tid>>4) -> float4
  {
    int t = tid & 15, nq = tid >> 4;
    int gn = n0 + nq * 4;
    if (gn < Nn) {
      float4 v = make_float4(pt[t][nq * 4 + 0], pt[t][nq * 4 + 1],
                             pt[t][nq * 4 + 2], pt[t][nq * 4 + 3]);
      *(float4*)(PhiT + (size_t)t * Nn + gn) = v;
    }
  }
  // XeT write: thread (c = tid>>2) covers 16 n's as 4x uint4
  {
    int c = tid >> 2, nb = (tid & 3) * 16;
    for (int q = 0; q < 4; ++q) {
      int nl = nb + q * 4;
      int gn = n0 + nl;
      if (gn >= Nn) break;
      unsigned int pu[4];
#pragma unroll
      for (int j = 0; j < 4; ++j) {
        int n = nl + j;
        float v;
        if (c < Hh) v = hrow[n][c];
        else if (c == 40) v = 1.f;
        else if (c < 49) v = xs[n][c - 41];
        else if (c == 49) v = ys[n];
        else v = 0.f;
        _Float16 hi = (_Float16)v;
        _Float16 lo = (_Float16)(v - (float)hi);
        pu[j] = ((unsigned int)__builtin_bit_cast(unsigned short, lo) << 16)
              |  (unsigned int)__builtin_bit_cast(unsigned short, hi);
      }
      *(uint4*)(XeT + (size_t)c * Nn + gn) =
          make_uint4(pu[0], pu[1], pu[2], pu[3]);
    }
  }
}

// ---------------- Kernel 1: MFMA Gram via LDS-staged swizzled tiles ----------------
// M = i*16+t, N = j (4 tiles), K = n. 2-term f16 split, 3 MFMA products.
// LDS tiles: xe [64 rows c][32 k-dwords], phi [16 rows t][32 k-f32];
// 16B granule XOR swizzle phys = g ^ (row&7), applied on the global source
// (global_load_lds writes linearly) and on every ds_read.
__device__ __forceinline__ void gload16(const void* g, void* l) {
  __builtin_amdgcn_global_load_lds(
      (const __attribute__((address_space(1))) unsigned int*)g,
      (__attribute__((address_space(3))) unsigned int*)l, 16, 0, 0);
}

__device__ __forceinline__ void unpack8(u32x4 a, u32x4 b, f16x8& hi, f16x8& lo) {
  u16x8 vh, vl;
#pragma unroll
  for (int e = 0; e < 4; ++e) {
    vh[e] = (unsigned short)(a[e] & 0xffffu);
    vl[e] = (unsigned short)(a[e] >> 16);
    vh[4 + e] = (unsigned short)(b[e] & 0xffffu);
    vl[4 + e] = (unsigned short)(b[e] >> 16);
  }
  hi = __builtin_bit_cast(f16x8, vh);
  lo = __builtin_bit_cast(f16x8, vl);
}

__device__ __forceinline__ void buildA(u32x4 a, u32x4 b, const float* ph,
                                       f16x8& ah, f16x8& al) {
  unsigned int u8[8];
#pragma unroll
  for (int e = 0; e < 4; ++e) { u8[e] = a[e]; u8[4 + e] = b[e]; }
#pragma unroll
  for (int e = 0; e < 8; ++e) {
    unsigned int u = u8[e];
    float hi = (float)__builtin_bit_cast(_Float16, (unsigned short)(u & 0xffffu));
    float lo = (float)__builtin_bit_cast(_Float16, (unsigned short)(u >> 16));
    float v = ph[e] * (hi + lo);
    _Float16 h = (_Float16)v;
    ah[e] = h;
    al[e] = (_Float16)(v - (float)h);
  }
}

__global__ __launch_bounds__(256, 2)
void gram_mfma(const float* __restrict__ PhiT, const unsigned int* __restrict__ XeT,
               float* __restrict__ P, int CH)
{
  __shared__ __align__(16) unsigned int xe_lds[2][2048];  // 8KB per buf
  __shared__ __align__(16) float phi_lds[2][512];         // 2KB per buf

  int tid = threadIdx.x;
  int l = tid & 63, w = tid >> 6;
  int lr = l >> 3, lp = l & 7;      // stage: row-in-instr, granule slot
  int gsw = lp ^ lr;                // logical granule at this slot
  int l15 = l & 15, lg = l >> 4;
  int bM = blockIdx.x, c = blockIdx.y;
  int n0 = c * CH;
  int rem = Nn - n0; if (rem > CH) rem = CH;
  int nsteps = rem >> 5;
  int i0 = bM * 13;

  // per-lane pre-swizzled global stage pointers (advance 32 dwords/step)
  const unsigned int* gx0 = XeT + (size_t)(16 * w + lr) * Nn + n0 + 4 * gsw;
  const unsigned int* gx1 = XeT + (size_t)(16 * w + 8 + lr) * Nn + n0 + 4 * gsw;
  const float* gp = PhiT + (size_t)(8 * w + lr) * Nn + n0 + 4 * gsw;

#define STAGE(nxt) do {                                   \
    gload16(gx0, &xe_lds[nxt][(2 * w) * 256]);            \
    gload16(gx1, &xe_lds[nxt][(2 * w + 1) * 256]);        \
    if (w < 2) gload16(gp, &phi_lds[nxt][w * 256]);       \
    gx0 += 32; gx1 += 32; gp += 32;                       \
  } while (0)

  // swizzled ds_read byte offsets
  int s1 = (2 * lg) ^ (l15 & 7), s2 = (2 * lg + 1) ^ (l15 & 7);
  int off_p0 = (l15 * 32 + 4 * s1) * 4, off_p1 = (l15 * 32 + 4 * s2) * 4;
  int off_b0[4], off_b1[4];
#pragma unroll
  for (int nt = 0; nt < 4; ++nt) {
    off_b0[nt] = ((l15 + 16 * nt) * 32 + 4 * s1) * 4;
    off_b1[nt] = ((l15 + 16 * nt) * 32 + 4 * s2) * 4;
  }
  int off_a0[4], off_a1[4];
#pragma unroll
  for (int mi = 0; mi < 4; ++mi) {
    int i = i0 + 4 * w + mi;   // dead tiles (>=52) read zero rows
    int a1 = (2 * lg) ^ (i & 7), a2 = (2 * lg + 1) ^ (i & 7);
    off_a0[mi] = (i * 32 + 4 * a1) * 4;
    off_a1[mi] = (i * 32 + 4 * a2) * 4;
  }

  f32x4 acc[4][4];
#pragma unroll
  for (int mi = 0; mi < 4; ++mi)
#pragma unroll
    for (int nt = 0; nt < 4; ++nt) acc[mi][nt] = (f32x4){0.f, 0.f, 0.f, 0.f};

  STAGE(0);
  __syncthreads();

  for (int s = 0; s < nsteps; ++s) {
    int cur = s & 1;
    if (s + 1 < nsteps) STAGE(cur ^ 1);

    const char* xb = (const char*)&xe_lds[cur][0];
    const char* pb = (const char*)&phi_lds[cur][0];
    f32x4 p0 = *(const f32x4*)(pb + off_p0);
    f32x4 p1 = *(const f32x4*)(pb + off_p1);
    float ph[8] = {p0[0], p0[1], p0[2], p0[3], p1[0], p1[1], p1[2], p1[3]};

    f16x8 bh[4], bl[4];
#pragma unroll
    for (int nt = 0; nt < 4; ++nt) {
      u32x4 lo4 = *(const u32x4*)(xb + off_b0[nt]);
      u32x4 hi4 = *(const u32x4*)(xb + off_b1[nt]);
      unpack8(lo4, hi4, bh[nt], bl[nt]);
    }
#pragma unroll
    for (int mi = 0; mi < 4; ++mi) {
      u32x4 a0 = *(const u32x4*)(xb + off_a0[mi]);   // 16-lane broadcast
      u32x4 a1 = *(const u32x4*)(xb + off_a1[mi]);
      f16x8 ah, al;
      buildA(a0, a1, ph, ah, al);
#pragma unroll
      for (int nt = 0; nt < 4; ++nt) {
        acc[mi][nt] = __builtin_amdgcn_mfma_f32_16x16x32_f16(ah, bh[nt], acc[mi][nt], 0, 0, 0);
        acc[mi][nt] = __builtin_amdgcn_mfma_f32_16x16x32_f16(ah, bl[nt], acc[mi][nt], 0, 0, 0);
        acc[mi][nt] = __builtin_amdgcn_mfma_f32_16x16x32_f16(al, bh[nt], acc[mi][nt], 0, 0, 0);
      }
    }
    __syncthreads();
  }
#undef STAGE

  // epilogue: C row = t = lg*4+r, col = j (verified C map)
  float* Pc = P + (size_t)c * CSZ;
#pragma unroll
  for (int mi = 0; mi < 4; ++mi) {
    int mloc = 4 * w + mi;
    if (mloc < 13) {
      int i = i0 + mloc;
#pragma unroll
      for (int nt = 0; nt < 4; ++nt) {
        int j = nt * 16 + l15;
#pragma unroll
        for (int r = 0; r < 4; ++r)
          Pc[(i * 16 + lg * 4 + r) * 64 + j] = acc[mi][nt][r];
      }
    }
  }
}

// ---------------- Kernel 2a/2b: chunk-partial reduction ----------------
__global__ __launch_bounds__(256)
void reduce_a(const float4* __restrict__ P4, int nchunks, float4* __restrict__ part4)
{
  int g = blockIdx.y;                               // 0..7
  int idx = blockIdx.x * 256 + threadIdx.x;         // 52 blocks cover CSZ/4
  int per = (nchunks + 7) / 8;
  int c0 = g * per, c1 = c0 + per; if (c1 > nchunks) c1 = nchunks;
  float4 s = make_float4(0.f, 0.f, 0.f, 0.f);
  for (int cc = c0; cc < c1; ++cc) {
    float4 v = P4[(size_t)cc * (CSZ / 4) + idx];
    s.x += v.x; s.y += v.y; s.z += v.z; s.w += v.w;
  }
  part4[(size_t)g * (CSZ / 4) + idx] = s;
}

__global__ __launch_bounds__(256)
void reduce_b(const float4* __restrict__ part4, float4* __restrict__ acc4)
{
  int idx = blockIdx.x * 256 + threadIdx.x;
  float4 s = make_float4(0.f, 0.f, 0.f, 0.f);
#pragma unroll
  for (int g = 0; g < 8; ++g) {
    float4 v = part4[(size_t)g * (CSZ / 4) + idx];
    s.x += v.x; s.y += v.y; s.z += v.z; s.w += v.w;
  }
  acc4[idx] = s;
}

// ---------------- Kernel 3: finalize (GJ inverse etc.) ----------------
__global__ __launch_bounds__(256)
void finalize_kernel(const float* __restrict__ acc, const float* __restrict__ epsA,
                     const float* __restrict__ epsB, const float* __restrict__ zetA,
                     const float* __restrict__ zetB, float* __restrict__ out)
{
  int t = blockIdx.x;
  int tid = threadIdx.x;
  __shared__ float G[HP1][84];          // [M | I] augmented
  __shared__ float As[HP1][HP1 + 1];
  __shared__ float bs[HP1];
  __shared__ float colk[HP1];
  __shared__ float red[256];
  __shared__ float wmv[HP1];
  __shared__ float rowv[4][HP1 + 1];
  __shared__ float mus[Dd];

  float epsExp = epsA[t] / epsB[t];
  float zetaExp = zetA[t] / zetB[t];

  for (int idx = tid; idx < HP1 * HP1; idx += 256) {
    int i = idx / HP1, j = idx % HP1;
    float a = acc[AIDX(i, t, j)];
    As[i][j] = a;
    G[i][j] = epsExp * a + (i == j ? zetaExp : 0.f);
    G[i][41 + j] = (i == j) ? 1.f : 0.f;
  }
  for (int idx = tid; idx < HP1; idx += 256) {
    G[idx][82] = 0.f; G[idx][83] = 0.f;
    bs[idx] = acc[AIDX(idx, t, 49)];
  }
  __syncthreads();

  int c = tid % HP1;         // 0..40
  int ig = tid / HP1;        // 0..6; ig<6 active
  int irow0 = ig * 7;

  for (int k = 0; k < HP1; ++k) {
    float pivinv = 1.f / G[k][k];
    if (tid >= 1 && tid <= HP1) G[k][k + tid] *= pivinv;
    if (tid < HP1) colk[tid] = (tid == k) ? 0.f : G[tid][k];
    __syncthreads();
    if (ig < 6) {
      int j = k + 1 + c;
      float pk = G[k][j];
#pragma unroll
      for (int r = 0; r < 7; ++r) {
        int i = irow0 + r;
        if (i < HP1 && i != k) G[i][j] = fmaf(-colk[i], pk, G[i][j]);
      }
    }
    __syncthreads();
  }

  for (int idx = tid; idx < HP1 * HP1; idx += 256) {
    int i = idx / HP1, j = idx % HP1;
    out[OFF_WS + (t * HP1 + i) * HP1 + j] = G[i][41 + j];
  }
  if (tid < HP1) {
    float s = 0.f;
    for (int j = 0; j < HP1; ++j) s += G[tid][41 + j] * bs[j];
    float w = zetaExp * s;
    wmv[tid] = w;
    out[OFF_WM + t * HP1 + tid] = w;
  }
  __syncthreads();
  float lt2 = 0.f;
  for (int idx = tid; idx < HP1 * HP1; idx += 256) {
    int i = idx / HP1, j = idx % HP1;
    lt2 += As[i][j] * G[i][41 + j];
  }
  red[tid] = lt2; __syncthreads();
  for (int s = 128; s > 0; s >>= 1) {
    if (tid < s) red[tid] += red[tid + s];
    __syncthreads();
  }
  float t2v = red[0];
  if (tid < HP1) {
    float w = wmv[tid];
    float aw = 0.f;
    for (int j = 0; j < HP1; ++j) aw += As[tid][j] * wmv[j];
    rowv[0][tid] = w * bs[tid];
    rowv[1][tid] = w * w;
    rowv[2][tid] = G[tid][41 + tid];
    rowv[3][tid] = w * aw;
  }
  __syncthreads();

  float sp = acc[AIDX(40, t, 40)];
  float kap = 1000.f + sp;
  float syy = acc[AIDX(49, t, 49)];

  if (tid == 0) {
    float wb = 0.f, wn = 0.f, trc = 0.f, quad = 0.f;
    for (int i = 0; i < HP1; ++i) {
      wb += rowv[0][i]; wn += rowv[1][i]; trc += rowv[2][i]; quad += rowv[3][i];
    }
    float t1 = syy - 2.f * wb + quad;
    out[OFF_BG1 + t] = 1.f + sp;
    float rest = 0.f;
    for (int u = t + 1; u < Tt; ++u) rest += acc[AIDX(40, u, 40)];
    out[OFF_BG2 + t] = 1.f + rest;
    out[OFF_KAPPA + t] = kap;
    out[OFF_NU + t] = sp + 100.f;
    out[OFF_ZA + t] = zetA[t] + 0.5f * (float)HP1;
    out[OFF_ZB + t] = zetB[t] + 0.5f * (wn + trc);
    out[OFF_EA + t] = epsA[t] + 0.5f * sp;
    out[OFF_EB + t] = epsB[t] + 0.5f * (t1 + t2v);
  }
  if (tid < Dd) {
    float m = acc[AIDX(40, t, 41 + tid)] / kap;
    mus[tid] = m;
    out[OFF_MU + tid * Tt + t] = m;
  }
  __syncthreads();
  if (tid < Dd * Dd) {
    int i = tid / Dd, j = tid % Dd;
    float S = acc[AIDX(41 + i, t, 41 + j)];
    float v = (i == j ? 500.f : 0.f) + S - kap * mus[i] * mus[j];
    out[OFF_PSI + (i * Dd + j) * Tt + t] = v;
  }
}

extern "C" void kernel_launch(void* const* d_in, const int* in_sizes, int n_in,
                              void* d_out, int out_size, void* d_ws, size_t ws_size,
                              hipStream_t stream) {
  const float* Phi = (const float*)d_in[1];
  const float* Xd  = (const float*)d_in[2];
  const float* Yd  = (const float*)d_in[3];
  const float* W   = (const float*)d_in[4];
  const float* bb  = (const float*)d_in[5];
  const float* eA  = (const float*)d_in[6];
  const float* eB  = (const float*)d_in[7];
  const float* zA  = (const float*)d_in[8];
  const float* zB  = (const float*)d_in[9];
  float* out = (float*)d_out;
  float* ws  = (float*)d_ws;

  unsigned int* XeT = (unsigned int*)(ws + XET_OFF);
  float* PhiT    = ws + PHIT_OFF;
  float* acc_red = ws + ACC_OFF;
  float* part    = ws + PART_OFF;
  float* P       = ws + P_OFF;

  // adapt chunk count to workspace (deterministic, graph-safe)
  long maxChunks = ((long)(ws_size / 4) - (long)P_OFF) / CSZ;
  if (maxChunks < 1) maxChunks = 1;
  long sp = (3125 + maxChunks - 1) / maxChunks;   // 32-k steps per chunk
  if (sp < 13) sp = 13;                           // cap chunk count (~241 max)
  int CH = (int)(32 * sp);
  int KCe = (Nn + CH - 1) / CH;

  hipLaunchKernelGGL(elm_expand, dim3((Nn + 63) / 64), dim3(256), 0, stream,
                     Phi, Xd, Yd, W, bb, XeT, PhiT);
  hipLaunchKernelGGL(gram_mfma, dim3(4, KCe), dim3(256), 0, stream,
                     PhiT, XeT, P, CH);
  hipLaunchKernelGGL(reduce_a, dim3(52, 8), dim3(256), 0, stream,
                     (const float4*)P, KCe, (float4*)part);
  hipLaunchKernelGGL(reduce_b, dim3(52), dim3(256), 0, stream,
                     (const float4*)part, (float4*)acc_red);
  hipLaunchKernelGGL(finalize_kernel, dim3(Tt), dim3(256), 0, stream,
                     acc_red, eA, eB, zA, zB, out);
}

// Round 3
// 177.642 us; speedup vs baseline: 1.1643x; 1.0470x over previous
//
#include <hip/hip_runtime.h>

#define Nn 100000
#define Tt 16
#define Dd 8
#define Hh 40
#define HP1 41

// ---- workspace layout (float slots) ----
#define CSZ 53248                      // 52*16*64 floats per chunk-partial
#define XEF_OFF  0                     // XeF32 [64][Nn] f32
#define XEH_OFF  (XEF_OFF + 64 * Nn)   // XeHi [64][Nn] f16 -> 32*Nn float slots
#define XEL_OFF  (XEH_OFF + 32 * Nn)   // XeLo [64][Nn] f16
#define PHIT_OFF (XEL_OFF + 32 * Nn)   // PhiT [16][Nn] f32
#define PART_OFF (PHIT_OFF + 16 * Nn)  // 8 * CSZ partials
#define P_OFF    (PART_OFF + 8 * CSZ)  // chunk partials

// output offsets (flat, return order)
#define OFF_BG1   0
#define OFF_BG2   16
#define OFF_MU    32
#define OFF_KAPPA 160
#define OFF_NU    176
#define OFF_PSI   192
#define OFF_WM    1216
#define OFF_WS    1872
#define OFF_ZA    28768
#define OFF_ZB    28784
#define OFF_EA    28800
#define OFF_EB    28816

typedef _Float16 f16x8 __attribute__((ext_vector_type(8)));
typedef float f32x4 __attribute__((ext_vector_type(4)));
typedef unsigned int u32x4 __attribute__((ext_vector_type(4)));

// A-index into partials: value A[t][i][j] at ((i*16+t)*64)+j
#define AIDX(i, t, j) ((((i) * 16 + (t)) * 64) + (j))

// ---------------- Kernel 0: ELM expansion -> XeF32 + XeHi/XeLo planes + PhiT ------
// Xe row layout c: [h0..h39, 1, x0..x7, y, 0...0] (c=50..63 zero)
__global__ __launch_bounds__(256)
void elm_expand(const float* __restrict__ Phi, const float* __restrict__ Xd,
                const float* __restrict__ Yd, const float* __restrict__ W,
                const float* __restrict__ bb, float* __restrict__ XeF32,
                unsigned short* __restrict__ XeHi, unsigned short* __restrict__ XeLo,
                float* __restrict__ PhiT)
{
  __shared__ float sW[Dd * Hh];
  __shared__ float sb[Hh];
  __shared__ float xs[64][9];
  __shared__ float ys[64];
  __shared__ float hrow[64][41];
  __shared__ float pt[16][68];
  int tid = threadIdx.x;
  int n0 = blockIdx.x * 64;

  for (int i = tid; i < Dd * Hh; i += 256) sW[i] = W[i];
  if (tid < Hh) sb[tid] = bb[tid];
  if (tid < 128) {
    int nl = tid >> 1, h4 = (tid & 1) * 4;
    int gn = n0 + nl;
    float4 v = (gn < Nn) ? *(const float4*)(Xd + (size_t)gn * 8 + h4)
                         : make_float4(0.f, 0.f, 0.f, 0.f);
    xs[nl][h4 + 0] = v.x; xs[nl][h4 + 1] = v.y;
    xs[nl][h4 + 2] = v.z; xs[nl][h4 + 3] = v.w;
  }
  if (tid < 64) { int gn = n0 + tid; ys[tid] = (gn < Nn) ? Yd[gn] : 0.f; }
  {
    int nl = tid >> 2, q = tid & 3;
    int gn = n0 + nl;
    float4 v = (gn < Nn) ? *(const float4*)(Phi + (size_t)gn * 16 + q * 4)
                         : make_float4(0.f, 0.f, 0.f, 0.f);
    pt[q * 4 + 0][nl] = v.x; pt[q * 4 + 1][nl] = v.y;
    pt[q * 4 + 2][nl] = v.z; pt[q * 4 + 3][nl] = v.w;
  }
  __syncthreads();
  // sigmoids: thread -> (n, 10 h's)
  {
    int nl = tid >> 2, hq = (tid & 3) * 10;
    for (int hh = 0; hh < 10; ++hh) {
      int h = hq + hh;
      float z = sb[h];
#pragma unroll
      for (int d = 0; d < 8; ++d) z = fmaf(xs[nl][d], sW[d * Hh + h], z);
      hrow[nl][h] = 1.f / (1.f + __expf(-z));
    }
  }
  __syncthreads();
  // PhiT write: thread (t = tid&15, nq = tid>>4) -> float4
  {
    int t = tid & 15, nq = tid >> 4;
    int gn = n0 + nq * 4;
    if (gn < Nn) {
      float4 v = make_float4(pt[t][nq * 4 + 0], pt[t][nq * 4 + 1],
                             pt[t][nq * 4 + 2], pt[t][nq * 4 + 3]);
      *(float4*)(PhiT + (size_t)t * Nn + gn) = v;
    }
  }
  // Xe planes: thread (c = tid>>2, seg = tid&3) covers 16 n's
  {
    int cidx = tid >> 2, seg = tid & 3;
    int nl0 = seg * 16;
    float vv[16];
#pragma unroll
    for (int j = 0; j < 16; ++j) {
      int n = nl0 + j;
      float v;
      if (cidx < Hh) v = hrow[n][cidx];
      else if (cidx == 40) v = 1.f;
      else if (cidx < 49) v = xs[n][cidx - 41];
      else if (cidx == 49) v = ys[n];
      else v = 0.f;
      vv[j] = v;
    }
#pragma unroll
    for (int q2 = 0; q2 < 4; ++q2) {
      int gn = n0 + nl0 + q2 * 4;
      if (gn < Nn)
        *(float4*)(XeF32 + (size_t)cidx * Nn + gn) =
            make_float4(vv[q2 * 4], vv[q2 * 4 + 1], vv[q2 * 4 + 2], vv[q2 * 4 + 3]);
    }
    unsigned short hs[16], ls[16];
#pragma unroll
    for (int j = 0; j < 16; ++j) {
      _Float16 h = (_Float16)vv[j];
      float r = vv[j] - (float)h;
      _Float16 lo = (_Float16)r;
      hs[j] = __builtin_bit_cast(unsigned short, h);
      ls[j] = __builtin_bit_cast(unsigned short, lo);
    }
#pragma unroll
    for (int q2 = 0; q2 < 2; ++q2) {
      int gn = n0 + nl0 + q2 * 8;
      if (gn < Nn) {
        uint4 uh, ul;
        uh.x = hs[q2*8+0] | ((unsigned)hs[q2*8+1] << 16);
        uh.y = hs[q2*8+2] | ((unsigned)hs[q2*8+3] << 16);
        uh.z = hs[q2*8+4] | ((unsigned)hs[q2*8+5] << 16);
        uh.w = hs[q2*8+6] | ((unsigned)hs[q2*8+7] << 16);
        ul.x = ls[q2*8+0] | ((unsigned)ls[q2*8+1] << 16);
        ul.y = ls[q2*8+2] | ((unsigned)ls[q2*8+3] << 16);
        ul.z = ls[q2*8+4] | ((unsigned)ls[q2*8+5] << 16);
        ul.w = ls[q2*8+6] | ((unsigned)ls[q2*8+7] << 16);
        *(uint4*)(XeHi + (size_t)cidx * Nn + gn) = uh;
        *(uint4*)(XeLo + (size_t)cidx * Nn + gn) = ul;
      }
    }
  }
}

// ---------------- Kernel 1: MFMA Gram, pre-split planes, LDS dbuf ----------------
// M = i*16+t (A rows = t), N = j (4 tiles), K = n. Products ah*bh + ah*bl + al*bh.
// LDS per buffer (12KB): Bhi[64][32]f16 @0, Blo @4096, A f32[16][32] @8192,
// phi f32[16][32] @10240. B swizzle: granule p = g ^ ((row>>1)&3) (4 granules/row).
// phi swizzle: p = g ^ (row&7) (8 granules/row). A unswizzled (broadcast reads).
__device__ __forceinline__ void gload16(const void* g, void* l) {
  __builtin_amdgcn_global_load_lds(
      (const __attribute__((address_space(1))) unsigned int*)g,
      (__attribute__((address_space(3))) unsigned int*)l, 16, 0, 0);
}

__global__ __launch_bounds__(256, 2)
void gram_mfma(const float* __restrict__ PhiT, const float* __restrict__ XeF32,
               const unsigned short* __restrict__ XeHi,
               const unsigned short* __restrict__ XeLo,
               float* __restrict__ P, int CH, int KCe)
{
  __shared__ __align__(16) char smem[2][12288];

  // XCD-co-locating decode: chunk-siblings (4 bM) get HW ids differing by 8.
  int id = blockIdx.x;
  int low3 = id & 7, rest = id >> 3;
  int bM = rest & 3, chigh = rest >> 2;
  int c = chigh * 8 + low3;
  if (c >= KCe) return;

  int tid = threadIdx.x;
  int l = tid & 63, w = tid >> 6;
  int l15 = l & 15, lg = l >> 4;
  int n0 = c * CH;
  int rem = Nn - n0; if (rem > CH) rem = CH;
  int nsteps = rem >> 5;
  int i0 = bM * 13;

  // staging: ids 0-3 Bhi, 4-7 Blo, 8-9 A(f32, rows i0..i0+15), 10-11 phi
  const char* gp[3];
  int gstep[3];
  int ldoff[3];
  {
    int idq = w * 3;
#pragma unroll
    for (int q = 0; q < 3; ++q) {
      int sid = idq + q;
      ldoff[q] = sid * 1024;
      if (sid < 8) {
        int qq = sid & 3;
        int row = 16 * qq + (l >> 2);
        int g = (l & 3) ^ ((l >> 3) & 3);          // pre-swizzled source granule
        const unsigned short* basep = (sid < 4) ? XeHi : XeLo;
        gp[q] = (const char*)(basep + (size_t)row * Nn + n0 + 8 * g);
        gstep[q] = 64;
      } else if (sid < 10) {
        int qq = sid - 8;
        int row = 8 * qq + (l >> 3);
        gp[q] = (const char*)(XeF32 + (size_t)(i0 + row) * Nn + n0 + 4 * (l & 7));
        gstep[q] = 128;
      } else {
        int qq = sid - 10;
        int row = 8 * qq + (l >> 3);
        int g = (l & 7) ^ (l >> 3);
        gp[q] = (const char*)(PhiT + (size_t)row * Nn + n0 + 4 * g);
        gstep[q] = 128;
      }
    }
  }

#define STAGE(buf) do {                          \
    char* db = &smem[buf][0];                    \
    gload16(gp[0], db + ldoff[0]); gp[0] += gstep[0]; \
    gload16(gp[1], db + ldoff[1]); gp[1] += gstep[1]; \
    gload16(gp[2], db + ldoff[2]); gp[2] += gstep[2]; \
  } while (0)

  // read offsets (bytes)
  int sB = (l15 >> 1) & 3;
  int off_b[4];
#pragma unroll
  for (int nt = 0; nt < 4; ++nt)
    off_b[nt] = (l15 + 16 * nt) * 64 + 16 * (lg ^ sB);
  int off_a[4];
#pragma unroll
  for (int mi = 0; mi < 4; ++mi)
    off_a[mi] = 8192 + (4 * w + mi) * 128 + 32 * lg;
  int off_p0 = 10240 + l15 * 128 + 16 * ((2 * lg) ^ (l15 & 7));
  int off_p1 = 10240 + l15 * 128 + 16 * ((2 * lg + 1) ^ (l15 & 7));

  f32x4 acc[4][4];
#pragma unroll
  for (int mi = 0; mi < 4; ++mi)
#pragma unroll
    for (int nt = 0; nt < 4; ++nt) acc[mi][nt] = (f32x4){0.f, 0.f, 0.f, 0.f};

  STAGE(0);
  __syncthreads();

  for (int s = 0; s < nsteps; ++s) {
    int cur = s & 1;
    if (s + 1 < nsteps) STAGE(cur ^ 1);

    const char* base = &smem[cur][0];
    f32x4 p0 = *(const f32x4*)(base + off_p0);
    f32x4 p1 = *(const f32x4*)(base + off_p1);
    f16x8 bh[4], bl[4];
#pragma unroll
    for (int nt = 0; nt < 4; ++nt) {
      bh[nt] = *(const f16x8*)(base + off_b[nt]);
      bl[nt] = *(const f16x8*)(base + 4096 + off_b[nt]);
    }
#pragma unroll
    for (int mi = 0; mi < 4; ++mi) {
      f32x4 x0 = *(const f32x4*)(base + off_a[mi]);        // broadcast
      f32x4 x1 = *(const f32x4*)(base + off_a[mi] + 16);
      float v0 = p0[0] * x0[0], v1 = p0[1] * x0[1];
      float v2 = p0[2] * x0[2], v3 = p0[3] * x0[3];
      float v4 = p1[0] * x1[0], v5 = p1[1] * x1[1];
      float v6 = p1[2] * x1[2], v7 = p1[3] * x1[3];
      auto h0 = __builtin_amdgcn_cvt_pkrtz(v0, v1);
      auto h1 = __builtin_amdgcn_cvt_pkrtz(v2, v3);
      auto h2 = __builtin_amdgcn_cvt_pkrtz(v4, v5);
      auto h3 = __builtin_amdgcn_cvt_pkrtz(v6, v7);
      float r0 = v0 - (float)h0[0], r1 = v1 - (float)h0[1];
      float r2 = v2 - (float)h1[0], r3 = v3 - (float)h1[1];
      float r4 = v4 - (float)h2[0], r5 = v5 - (float)h2[1];
      float r6 = v6 - (float)h3[0], r7 = v7 - (float)h3[1];
      auto e0 = __builtin_amdgcn_cvt_pkrtz(r0, r1);
      auto e1 = __builtin_amdgcn_cvt_pkrtz(r2, r3);
      auto e2 = __builtin_amdgcn_cvt_pkrtz(r4, r5);
      auto e3 = __builtin_amdgcn_cvt_pkrtz(r6, r7);
      u32x4 uh = {__builtin_bit_cast(unsigned int, h0), __builtin_bit_cast(unsigned int, h1),
                  __builtin_bit_cast(unsigned int, h2), __builtin_bit_cast(unsigned int, h3)};
      u32x4 ul = {__builtin_bit_cast(unsigned int, e0), __builtin_bit_cast(unsigned int, e1),
                  __builtin_bit_cast(unsigned int, e2), __builtin_bit_cast(unsigned int, e3)};
      f16x8 ah = __builtin_bit_cast(f16x8, uh);
      f16x8 al = __builtin_bit_cast(f16x8, ul);
#pragma unroll
      for (int nt = 0; nt < 4; ++nt) {
        acc[mi][nt] = __builtin_amdgcn_mfma_f32_16x16x32_f16(ah, bh[nt], acc[mi][nt], 0, 0, 0);
        acc[mi][nt] = __builtin_amdgcn_mfma_f32_16x16x32_f16(ah, bl[nt], acc[mi][nt], 0, 0, 0);
        acc[mi][nt] = __builtin_amdgcn_mfma_f32_16x16x32_f16(al, bh[nt], acc[mi][nt], 0, 0, 0);
      }
    }
    __syncthreads();
  }
#undef STAGE

  // epilogue: C row = t = lg*4+r, col = j (verified C map)
  float* Pc = P + (size_t)c * CSZ;
#pragma unroll
  for (int mi = 0; mi < 4; ++mi) {
    int mloc = 4 * w + mi;
    if (mloc < 13) {
      int i = i0 + mloc;
#pragma unroll
      for (int nt = 0; nt < 4; ++nt) {
        int j = nt * 16 + l15;
#pragma unroll
        for (int r = 0; r < 4; ++r)
          Pc[(i * 16 + lg * 4 + r) * 64 + j] = acc[mi][nt][r];
      }
    }
  }
}

// ---------------- Kernel 2: chunk-partial reduction (KCe -> 8 groups) ----------------
__global__ __launch_bounds__(256)
void reduce_a(const float4* __restrict__ P4, int nchunks, float4* __restrict__ part4)
{
  int g = blockIdx.y;                               // 0..7
  int idx = blockIdx.x * 256 + threadIdx.x;         // 52 blocks cover CSZ/4
  int per = (nchunks + 7) / 8;
  int c0 = g * per, c1 = c0 + per; if (c1 > nchunks) c1 = nchunks;
  float4 s = make_float4(0.f, 0.f, 0.f, 0.f);
  for (int cc = c0; cc < c1; ++cc) {
    float4 v = P4[(size_t)cc * (CSZ / 4) + idx];
    s.x += v.x; s.y += v.y; s.z += v.z; s.w += v.w;
  }
  part4[(size_t)g * (CSZ / 4) + idx] = s;
}

// ---------------- Kernel 3: finalize (GJ inverse etc.), sums 8 partials inline ------
__device__ __forceinline__ float accv(const float* __restrict__ part, int idx) {
  float s = 0.f;
#pragma unroll
  for (int g = 0; g < 8; ++g) s += part[g * CSZ + idx];
  return s;
}

__global__ __launch_bounds__(256)
void finalize_kernel(const float* __restrict__ part, const float* __restrict__ epsA,
                     const float* __restrict__ epsB, const float* __restrict__ zetA,
                     const float* __restrict__ zetB, float* __restrict__ out)
{
  int t = blockIdx.x;
  int tid = threadIdx.x;
  __shared__ float G[HP1][84];          // [M | I] augmented
  __shared__ float As[HP1][HP1 + 1];
  __shared__ float bs[HP1];
  __shared__ float colk[HP1];
  __shared__ float red[256];
  __shared__ float wmv[HP1];
  __shared__ float rowv[4][HP1 + 1];
  __shared__ float mus[Dd];

  float epsExp = epsA[t] / epsB[t];
  float zetaExp = zetA[t] / zetB[t];

  for (int idx = tid; idx < HP1 * HP1; idx += 256) {
    int i = idx / HP1, j = idx % HP1;
    float a = accv(part, AIDX(i, t, j));
    As[i][j] = a;
    G[i][j] = epsExp * a + (i == j ? zetaExp : 0.f);
    G[i][41 + j] = (i == j) ? 1.f : 0.f;
  }
  for (int idx = tid; idx < HP1; idx += 256) {
    G[idx][82] = 0.f; G[idx][83] = 0.f;
    bs[idx] = accv(part, AIDX(idx, t, 49));
  }
  __syncthreads();

  int c = tid % HP1;         // 0..40
  int ig = tid / HP1;        // 0..6; ig<6 active
  int irow0 = ig * 7;

  for (int k = 0; k < HP1; ++k) {
    float pivinv = 1.f / G[k][k];
    if (tid >= 1 && tid <= HP1) G[k][k + tid] *= pivinv;
    if (tid < HP1) colk[tid] = (tid == k) ? 0.f : G[tid][k];
    __syncthreads();
    if (ig < 6) {
      int j = k + 1 + c;
      float pk = G[k][j];
#pragma unroll
      for (int r = 0; r < 7; ++r) {
        int i = irow0 + r;
        if (i < HP1 && i != k) G[i][j] = fmaf(-colk[i], pk, G[i][j]);
      }
    }
    __syncthreads();
  }

  for (int idx = tid; idx < HP1 * HP1; idx += 256) {
    int i = idx / HP1, j = idx % HP1;
    out[OFF_WS + (t * HP1 + i) * HP1 + j] = G[i][41 + j];
  }
  if (tid < HP1) {
    float s = 0.f;
    for (int j = 0; j < HP1; ++j) s += G[tid][41 + j] * bs[j];
    float w = zetaExp * s;
    wmv[tid] = w;
    out[OFF_WM + t * HP1 + tid] = w;
  }
  __syncthreads();
  float lt2 = 0.f;
  for (int idx = tid; idx < HP1 * HP1; idx += 256) {
    int i = idx / HP1, j = idx % HP1;
    lt2 += As[i][j] * G[i][41 + j];
  }
  red[tid] = lt2; __syncthreads();
  for (int s = 128; s > 0; s >>= 1) {
    if (tid < s) red[tid] += red[tid + s];
    __syncthreads();
  }
  float t2v = red[0];
  if (tid < HP1) {
    float w = wmv[tid];
    float aw = 0.f;
    for (int j = 0; j < HP1; ++j) aw += As[tid][j] * wmv[j];
    rowv[0][tid] = w * bs[tid];
    rowv[1][tid] = w * w;
    rowv[2][tid] = G[tid][41 + tid];
    rowv[3][tid] = w * aw;
  }
  __syncthreads();

  float sp = accv(part, AIDX(40, t, 40));
  float kap = 1000.f + sp;
  float syy = accv(part, AIDX(49, t, 49));

  if (tid == 0) {
    float wb = 0.f, wn = 0.f, trc = 0.f, quad = 0.f;
    for (int i = 0; i < HP1; ++i) {
      wb += rowv[0][i]; wn += rowv[1][i]; trc += rowv[2][i]; quad += rowv[3][i];
    }
    float t1 = syy - 2.f * wb + quad;
    out[OFF_BG1 + t] = 1.f + sp;
    float rest = 0.f;
    for (int u = t + 1; u < Tt; ++u) rest += accv(part, AIDX(40, u, 40));
    out[OFF_BG2 + t] = 1.f + rest;            // ALPHA_DP = 1
    out[OFF_KAPPA + t] = kap;
    out[OFF_NU + t] = sp + 100.f;
    out[OFF_ZA + t] = zetA[t] + 0.5f * (float)HP1;
    out[OFF_ZB + t] = zetB[t] + 0.5f * (wn + trc);
    out[OFF_EA + t] = epsA[t] + 0.5f * sp;
    out[OFF_EB + t] = epsB[t] + 0.5f * (t1 + t2v);
  }
  if (tid < Dd) {
    float m = accv(part, AIDX(40, t, 41 + tid)) / kap;
    mus[tid] = m;
    out[OFF_MU + tid * Tt + t] = m;
  }
  __syncthreads();
  if (tid < Dd * Dd) {
    int i = tid / Dd, j = tid % Dd;
    float S = accv(part, AIDX(41 + i, t, 41 + j));
    float v = (i == j ? 500.f : 0.f) + S - kap * mus[i] * mus[j];
    out[OFF_PSI + (i * Dd + j) * Tt + t] = v;
  }
}

extern "C" void kernel_launch(void* const* d_in, const int* in_sizes, int n_in,
                              void* d_out, int out_size, void* d_ws, size_t ws_size,
                              hipStream_t stream) {
  const float* Phi = (const float*)d_in[1];
  const float* Xd  = (const float*)d_in[2];
  const float* Yd  = (const float*)d_in[3];
  const float* W   = (const float*)d_in[4];
  const float* bb  = (const float*)d_in[5];
  const float* eA  = (const float*)d_in[6];
  const float* eB  = (const float*)d_in[7];
  const float* zA  = (const float*)d_in[8];
  const float* zB  = (const float*)d_in[9];
  float* out = (float*)d_out;
  float* ws  = (float*)d_ws;

  float* XeF32 = ws + XEF_OFF;
  unsigned short* XeHi = (unsigned short*)(ws + XEH_OFF);
  unsigned short* XeLo = (unsigned short*)(ws + XEL_OFF);
  float* PhiT = ws + PHIT_OFF;
  float* part = ws + PART_OFF;
  float* P    = ws + P_OFF;

  // adapt chunk count to workspace (deterministic, graph-safe)
  long maxChunks = ((long)(ws_size / 4) - (long)P_OFF) / CSZ;
  if (maxChunks < 1) maxChunks = 1;
  long sp = (3125 + maxChunks - 1) / maxChunks;   // 32-k steps per chunk
  if (sp < 13) sp = 13;                           // cap chunk count (~241)
  int CH = (int)(32 * sp);
  int KCe = (Nn + CH - 1) / CH;
  int grid1 = 32 * ((KCe + 7) / 8);               // padded for XCD decode

  hipLaunchKernelGGL(elm_expand, dim3((Nn + 63) / 64), dim3(256), 0, stream,
                     Phi, Xd, Yd, W, bb, XeF32, XeHi, XeLo, PhiT);
  hipLaunchKernelGGL(gram_mfma, dim3(grid1), dim3(256), 0, stream,
                     PhiT, XeF32, XeHi, XeLo, P, CH, KCe);
  hipLaunchKernelGGL(reduce_a, dim3(52, 8), dim3(256), 0, stream,
                     (const float4*)P, KCe, (float4*)part);
  hipLaunchKernelGGL(finalize_kernel, dim3(Tt), dim3(256), 0, stream,
                     part, eA, eB, zA, zB, out);
}

// Round 4
// 170.599 us; speedup vs baseline: 1.2124x; 1.0413x over previous
//
#include <hip/hip_runtime.h>

#define Nn 100000
#define Tt 16
#define Dd 8
#define Hh 40
#define HP1 41

// ---- workspace layout (float slots) ----
#define CSZ 53248                      // 52*16*64 floats per chunk-partial
#define XEH_OFF  0                     // XeHi [64][Nn] f16 -> 32*Nn float slots
#define XEL_OFF  (XEH_OFF + 32 * Nn)   // XeLo [64][Nn] f16
#define PHIT_OFF (XEL_OFF + 32 * Nn)   // PhiT [16][Nn] f32
#define PART_OFF (PHIT_OFF + 16 * Nn)  // 8 * CSZ partials
#define P_OFF    (PART_OFF + 8 * CSZ)  // chunk partials

// output offsets (flat, return order)
#define OFF_BG1   0
#define OFF_BG2   16
#define OFF_MU    32
#define OFF_KAPPA 160
#define OFF_NU    176
#define OFF_PSI   192
#define OFF_WM    1216
#define OFF_WS    1872
#define OFF_ZA    28768
#define OFF_ZB    28784
#define OFF_EA    28800
#define OFF_EB    28816

typedef _Float16 f16x8 __attribute__((ext_vector_type(8)));
typedef float f32x4 __attribute__((ext_vector_type(4)));
typedef unsigned int u32x4 __attribute__((ext_vector_type(4)));

// A-index into partials: value A[t][i][j] at ((i*16+t)*64)+j
#define AIDX(i, t, j) ((((i) * 16 + (t)) * 64) + (j))

// ---------------- Kernel 0: ELM expansion -> XeHi/XeLo planes + PhiT ------
// Xe row layout c: [h0..h39, 1, x0..x7, y, 0...0] (c=50..63 zero)
__global__ __launch_bounds__(256)
void elm_expand(const float* __restrict__ Phi, const float* __restrict__ Xd,
                const float* __restrict__ Yd, const float* __restrict__ W,
                const float* __restrict__ bb,
                unsigned short* __restrict__ XeHi, unsigned short* __restrict__ XeLo,
                float* __restrict__ PhiT)
{
  __shared__ float sW[Dd * Hh];
  __shared__ float sb[Hh];
  __shared__ float xs[64][9];
  __shared__ float ys[64];
  __shared__ float hrow[64][41];
  __shared__ float pt[16][68];
  int tid = threadIdx.x;
  int n0 = blockIdx.x * 64;

  for (int i = tid; i < Dd * Hh; i += 256) sW[i] = W[i];
  if (tid < Hh) sb[tid] = bb[tid];
  if (tid < 128) {
    int nl = tid >> 1, h4 = (tid & 1) * 4;
    int gn = n0 + nl;
    float4 v = (gn < Nn) ? *(const float4*)(Xd + (size_t)gn * 8 + h4)
                         : make_float4(0.f, 0.f, 0.f, 0.f);
    xs[nl][h4 + 0] = v.x; xs[nl][h4 + 1] = v.y;
    xs[nl][h4 + 2] = v.z; xs[nl][h4 + 3] = v.w;
  }
  if (tid < 64) { int gn = n0 + tid; ys[tid] = (gn < Nn) ? Yd[gn] : 0.f; }
  {
    int nl = tid >> 2, q = tid & 3;
    int gn = n0 + nl;
    float4 v = (gn < Nn) ? *(const float4*)(Phi + (size_t)gn * 16 + q * 4)
                         : make_float4(0.f, 0.f, 0.f, 0.f);
    pt[q * 4 + 0][nl] = v.x; pt[q * 4 + 1][nl] = v.y;
    pt[q * 4 + 2][nl] = v.z; pt[q * 4 + 3][nl] = v.w;
  }
  __syncthreads();
  // sigmoids: thread -> (n, 10 h's)
  {
    int nl = tid >> 2, hq = (tid & 3) * 10;
    for (int hh = 0; hh < 10; ++hh) {
      int h = hq + hh;
      float z = sb[h];
#pragma unroll
      for (int d = 0; d < 8; ++d) z = fmaf(xs[nl][d], sW[d * Hh + h], z);
      hrow[nl][h] = 1.f / (1.f + __expf(-z));
    }
  }
  __syncthreads();
  // PhiT write: thread (t = tid&15, nq = tid>>4) -> float4
  {
    int t = tid & 15, nq = tid >> 4;
    int gn = n0 + nq * 4;
    if (gn < Nn) {
      float4 v = make_float4(pt[t][nq * 4 + 0], pt[t][nq * 4 + 1],
                             pt[t][nq * 4 + 2], pt[t][nq * 4 + 3]);
      *(float4*)(PhiT + (size_t)t * Nn + gn) = v;
    }
  }
  // Xe hi/lo planes: thread (c = tid>>2, seg = tid&3) covers 16 n's
  {
    int cidx = tid >> 2, seg = tid & 3;
    int nl0 = seg * 16;
    float vv[16];
#pragma unroll
    for (int j = 0; j < 16; ++j) {
      int n = nl0 + j;
      float v;
      if (cidx < Hh) v = hrow[n][cidx];
      else if (cidx == 40) v = 1.f;
      else if (cidx < 49) v = xs[n][cidx - 41];
      else if (cidx == 49) v = ys[n];
      else v = 0.f;
      vv[j] = v;
    }
    unsigned short hs[16], ls[16];
#pragma unroll
    for (int j = 0; j < 16; ++j) {
      _Float16 h = (_Float16)vv[j];
      float r = vv[j] - (float)h;
      _Float16 lo = (_Float16)r;
      hs[j] = __builtin_bit_cast(unsigned short, h);
      ls[j] = __builtin_bit_cast(unsigned short, lo);
    }
#pragma unroll
    for (int q2 = 0; q2 < 2; ++q2) {
      int gn = n0 + nl0 + q2 * 8;
      if (gn < Nn) {
        uint4 uh, ul;
        uh.x = hs[q2*8+0] | ((unsigned)hs[q2*8+1] << 16);
        uh.y = hs[q2*8+2] | ((unsigned)hs[q2*8+3] << 16);
        uh.z = hs[q2*8+4] | ((unsigned)hs[q2*8+5] << 16);
        uh.w = hs[q2*8+6] | ((unsigned)hs[q2*8+7] << 16);
        ul.x = ls[q2*8+0] | ((unsigned)ls[q2*8+1] << 16);
        ul.y = ls[q2*8+2] | ((unsigned)ls[q2*8+3] << 16);
        ul.z = ls[q2*8+4] | ((unsigned)ls[q2*8+5] << 16);
        ul.w = ls[q2*8+6] | ((unsigned)ls[q2*8+7] << 16);
        *(uint4*)(XeHi + (size_t)cidx * Nn + gn) = uh;
        *(uint4*)(XeLo + (size_t)cidx * Nn + gn) = ul;
      }
    }
  }
}

// ---------------- Kernel 1: MFMA Gram, 512-thr block = whole chunk ----------------
// One block per K-chunk. 8 waves cover all 52 i-rows (4x7 + 4x6 M-tiles).
// A rows are a SUBSET of B rows: the staged B hi/lo planes serve both operands.
// LDS per buffer (10KB): Bhi[64 rows][32k]f16 @0, Blo @4096, phi[16][32k]f32 @8192.
// Swizzle: B granule' = g ^ (row&3) (4x16B/row), phi granule' = g ^ (row&7)
// (8x16B/row); applied on the pre-swizzled global source (linear LDS dest) and
// on every ds_read with the same involution.
__device__ __forceinline__ void gload16(const void* g, void* l) {
  __builtin_amdgcn_global_load_lds(
      (const __attribute__((address_space(1))) unsigned int*)g,
      (__attribute__((address_space(3))) unsigned int*)l, 16, 0, 0);
}

__global__ __launch_bounds__(512, 2)
void gram_mfma(const float* __restrict__ PhiT,
               const unsigned short* __restrict__ XeHi,
               const unsigned short* __restrict__ XeLo,
               float* __restrict__ P, int CH)
{
  __shared__ __align__(16) char smem[2][10240];

  int tid = threadIdx.x;
  int c = blockIdx.x;
  int l = tid & 63, w = tid >> 6;
  int l15 = l & 15, lg = l >> 4;
  int n0 = c * CH;
  int rem = Nn - n0; if (rem > CH) rem = CH;
  int nsteps = rem >> 5;

  // per-wave M-tile range: waves 0-3 own 7 tiles, 4-7 own 6 (total 52)
  int MT  = (w < 4) ? 7 : 6;
  int i0w = (w < 4) ? 7 * w : 28 + 6 * (w - 4);

  // ---- staging decode: 640 granules of 16B (512 B-planes + 128 phi) ----
  // granule gid: lds byte = gid*16. gid<256: Bhi row gid>>2 slot gid&3;
  // gid<512: Blo; gid>=512: phi row (gid-512)>>3 slot (gid-512)&7.
  const char* g0; const char* g1 = nullptr;
  int ld0 = tid * 16, ld1 = (512 + tid) * 16;
  {
    int r = (tid & 255) >> 2, s = tid & 3;
    const unsigned short* bp = (tid < 256) ? XeHi : XeLo;
    g0 = (const char*)(bp + (size_t)r * Nn + n0 + 8 * (s ^ (r & 3)));
    if (tid < 128) {
      int t = tid >> 3, s2 = tid & 7;
      g1 = (const char*)(PhiT + (size_t)t * Nn + n0 + 4 * (s2 ^ (t & 7)));
    }
  }

#define STAGE(buf) do {                              \
    char* db = &smem[buf][0];                        \
    gload16(g0, db + ld0); g0 += 64;                 \
    if (tid < 128) { gload16(g1, db + ld1); g1 += 128; } \
  } while (0)

  // ---- read offsets (bytes) ----
  int off_b[4];
#pragma unroll
  for (int nt = 0; nt < 4; ++nt) {
    int j = l15 + 16 * nt;
    off_b[nt] = j * 64 + 16 * (lg ^ (j & 3));
  }
  int off_p0 = 8192 + l15 * 128 + 16 * ((2 * lg) ^ (l15 & 7));
  int off_p1 = 8192 + l15 * 128 + 16 * ((2 * lg + 1) ^ (l15 & 7));
  int off_a[7];
#pragma unroll
  for (int mi = 0; mi < 7; ++mi) {
    int i = i0w + mi;              // <= 52; rows >= 50 are exact zeros
    off_a[mi] = i * 64 + 16 * (lg ^ (i & 3));
  }

  f32x4 acc[7][4];
#pragma unroll
  for (int mi = 0; mi < 7; ++mi)
#pragma unroll
    for (int nt = 0; nt < 4; ++nt) acc[mi][nt] = (f32x4){0.f, 0.f, 0.f, 0.f};

  STAGE(0);
  __syncthreads();

  for (int s = 0; s < nsteps; ++s) {
    int cur = s & 1;
    if (s + 1 < nsteps) STAGE(cur ^ 1);

    const char* base = &smem[cur][0];
    f32x4 p0 = *(const f32x4*)(base + off_p0);
    f32x4 p1 = *(const f32x4*)(base + off_p1);
    float ph[8] = {p0[0], p0[1], p0[2], p0[3], p1[0], p1[1], p1[2], p1[3]};

    f16x8 bh[4], bl[4];
#pragma unroll
    for (int nt = 0; nt < 4; ++nt) {
      bh[nt] = *(const f16x8*)(base + off_b[nt]);
      bl[nt] = *(const f16x8*)(base + 4096 + off_b[nt]);
    }
#pragma unroll
    for (int mi = 0; mi < 7; ++mi) {
      if (mi >= MT) break;
      f16x8 xh = *(const f16x8*)(base + off_a[mi]);          // broadcast
      f16x8 xl = *(const f16x8*)(base + 4096 + off_a[mi]);   // broadcast
      float v0 = ph[0] * ((float)xh[0] + (float)xl[0]);
      float v1 = ph[1] * ((float)xh[1] + (float)xl[1]);
      float v2 = ph[2] * ((float)xh[2] + (float)xl[2]);
      float v3 = ph[3] * ((float)xh[3] + (float)xl[3]);
      float v4 = ph[4] * ((float)xh[4] + (float)xl[4]);
      float v5 = ph[5] * ((float)xh[5] + (float)xl[5]);
      float v6 = ph[6] * ((float)xh[6] + (float)xl[6]);
      float v7 = ph[7] * ((float)xh[7] + (float)xl[7]);
      auto h0 = __builtin_amdgcn_cvt_pkrtz(v0, v1);
      auto h1 = __builtin_amdgcn_cvt_pkrtz(v2, v3);
      auto h2 = __builtin_amdgcn_cvt_pkrtz(v4, v5);
      auto h3 = __builtin_amdgcn_cvt_pkrtz(v6, v7);
      float r0 = v0 - (float)h0[0], r1 = v1 - (float)h0[1];
      float r2 = v2 - (float)h1[0], r3 = v3 - (float)h1[1];
      float r4 = v4 - (float)h2[0], r5 = v5 - (float)h2[1];
      float r6 = v6 - (float)h3[0], r7 = v7 - (float)h3[1];
      auto e0 = __builtin_amdgcn_cvt_pkrtz(r0, r1);
      auto e1 = __builtin_amdgcn_cvt_pkrtz(r2, r3);
      auto e2 = __builtin_amdgcn_cvt_pkrtz(r4, r5);
      auto e3 = __builtin_amdgcn_cvt_pkrtz(r6, r7);
      u32x4 uh = {__builtin_bit_cast(unsigned int, h0), __builtin_bit_cast(unsigned int, h1),
                  __builtin_bit_cast(unsigned int, h2), __builtin_bit_cast(unsigned int, h3)};
      u32x4 ul = {__builtin_bit_cast(unsigned int, e0), __builtin_bit_cast(unsigned int, e1),
                  __builtin_bit_cast(unsigned int, e2), __builtin_bit_cast(unsigned int, e3)};
      f16x8 ah = __builtin_bit_cast(f16x8, uh);
      f16x8 al = __builtin_bit_cast(f16x8, ul);
#pragma unroll
      for (int nt = 0; nt < 4; ++nt) {
        acc[mi][nt] = __builtin_amdgcn_mfma_f32_16x16x32_f16(ah, bh[nt], acc[mi][nt], 0, 0, 0);
        acc[mi][nt] = __builtin_amdgcn_mfma_f32_16x16x32_f16(ah, bl[nt], acc[mi][nt], 0, 0, 0);
        acc[mi][nt] = __builtin_amdgcn_mfma_f32_16x16x32_f16(al, bh[nt], acc[mi][nt], 0, 0, 0);
      }
    }
    __syncthreads();
  }
#undef STAGE

  // epilogue: C row = t = lg*4+r, col = j (verified C map)
  float* Pc = P + (size_t)c * CSZ;
#pragma unroll
  for (int mi = 0; mi < 7; ++mi) {
    if (mi >= MT) break;
    int i = i0w + mi;
#pragma unroll
    for (int nt = 0; nt < 4; ++nt) {
      int j = nt * 16 + l15;
#pragma unroll
      for (int r = 0; r < 4; ++r)
        Pc[(i * 16 + lg * 4 + r) * 64 + j] = acc[mi][nt][r];
    }
  }
}

// ---------------- Kernel 2: chunk-partial reduction (KCe -> 8 groups) ----------------
__global__ __launch_bounds__(256)
void reduce_a(const float4* __restrict__ P4, int nchunks, float4* __restrict__ part4)
{
  int g = blockIdx.y;                               // 0..7
  int idx = blockIdx.x * 256 + threadIdx.x;         // 52 blocks cover CSZ/4
  int per = (nchunks + 7) / 8;
  int c0 = g * per, c1 = c0 + per; if (c1 > nchunks) c1 = nchunks;
  float4 s = make_float4(0.f, 0.f, 0.f, 0.f);
  for (int cc = c0; cc < c1; ++cc) {
    float4 v = P4[(size_t)cc * (CSZ / 4) + idx];
    s.x += v.x; s.y += v.y; s.z += v.z; s.w += v.w;
  }
  part4[(size_t)g * (CSZ / 4) + idx] = s;
}

// ---------------- Kernel 3: finalize (GJ inverse etc.), sums 8 partials inline ------
__device__ __forceinline__ float accv(const float* __restrict__ part, int idx) {
  float s = 0.f;
#pragma unroll
  for (int g = 0; g < 8; ++g) s += part[g * CSZ + idx];
  return s;
}

__global__ __launch_bounds__(256)
void finalize_kernel(const float* __restrict__ part, const float* __restrict__ epsA,
                     const float* __restrict__ epsB, const float* __restrict__ zetA,
                     const float* __restrict__ zetB, float* __restrict__ out)
{
  int t = blockIdx.x;
  int tid = threadIdx.x;
  __shared__ float G[HP1][84];          // [M | I] augmented
  __shared__ float As[HP1][HP1 + 1];
  __shared__ float bs[HP1];
  __shared__ float colk[HP1];
  __shared__ float red[256];
  __shared__ float wmv[HP1];
  __shared__ float rowv[4][HP1 + 1];
  __shared__ float mus[Dd];

  float epsExp = epsA[t] / epsB[t];
  float zetaExp = zetA[t] / zetB[t];

  for (int idx = tid; idx < HP1 * HP1; idx += 256) {
    int i = idx / HP1, j = idx % HP1;
    float a = accv(part, AIDX(i, t, j));
    As[i][j] = a;
    G[i][j] = epsExp * a + (i == j ? zetaExp : 0.f);
    G[i][41 + j] = (i == j) ? 1.f : 0.f;
  }
  for (int idx = tid; idx < HP1; idx += 256) {
    G[idx][82] = 0.f; G[idx][83] = 0.f;
    bs[idx] = accv(part, AIDX(idx, t, 49));
  }
  __syncthreads();

  int c = tid % HP1;         // 0..40
  int ig = tid / HP1;        // 0..6; ig<6 active
  int irow0 = ig * 7;

  for (int k = 0; k < HP1; ++k) {
    float pivinv = 1.f / G[k][k];
    if (tid >= 1 && tid <= HP1) G[k][k + tid] *= pivinv;
    if (tid < HP1) colk[tid] = (tid == k) ? 0.f : G[tid][k];
    __syncthreads();
    if (ig < 6) {
      int j = k + 1 + c;
      float pk = G[k][j];
#pragma unroll
      for (int r = 0; r < 7; ++r) {
        int i = irow0 + r;
        if (i < HP1 && i != k) G[i][j] = fmaf(-colk[i], pk, G[i][j]);
      }
    }
    __syncthreads();
  }

  for (int idx = tid; idx < HP1 * HP1; idx += 256) {
    int i = idx / HP1, j = idx % HP1;
    out[OFF_WS + (t * HP1 + i) * HP1 + j] = G[i][41 + j];
  }
  if (tid < HP1) {
    float s = 0.f;
    for (int j = 0; j < HP1; ++j) s += G[tid][41 + j] * bs[j];
    float w = zetaExp * s;
    wmv[tid] = w;
    out[OFF_WM + t * HP1 + tid] = w;
  }
  __syncthreads();
  float lt2 = 0.f;
  for (int idx = tid; idx < HP1 * HP1; idx += 256) {
    int i = idx / HP1, j = idx % HP1;
    lt2 += As[i][j] * G[i][41 + j];
  }
  red[tid] = lt2; __syncthreads();
  for (int s = 128; s > 0; s >>= 1) {
    if (tid < s) red[tid] += red[tid + s];
    __syncthreads();
  }
  float t2v = red[0];
  if (tid < HP1) {
    float w = wmv[tid];
    float aw = 0.f;
    for (int j = 0; j < HP1; ++j) aw += As[tid][j] * wmv[j];
    rowv[0][tid] = w * bs[tid];
    rowv[1][tid] = w * w;
    rowv[2][tid] = G[tid][41 + tid];
    rowv[3][tid] = w * aw;
  }
  __syncthreads();

  float sp = accv(part, AIDX(40, t, 40));
  float kap = 1000.f + sp;
  float syy = accv(part, AIDX(49, t, 49));

  if (tid == 0) {
    float wb = 0.f, wn = 0.f, trc = 0.f, quad = 0.f;
    for (int i = 0; i < HP1; ++i) {
      wb += rowv[0][i]; wn += rowv[1][i]; trc += rowv[2][i]; quad += rowv[3][i];
    }
    float t1 = syy - 2.f * wb + quad;
    out[OFF_BG1 + t] = 1.f + sp;
    float rest = 0.f;
    for (int u = t + 1; u < Tt; ++u) rest += accv(part, AIDX(40, u, 40));
    out[OFF_BG2 + t] = 1.f + rest;            // ALPHA_DP = 1
    out[OFF_KAPPA + t] = kap;
    out[OFF_NU + t] = sp + 100.f;
    out[OFF_ZA + t] = zetA[t] + 0.5f * (float)HP1;
    out[OFF_ZB + t] = zetB[t] + 0.5f * (wn + trc);
    out[OFF_EA + t] = epsA[t] + 0.5f * sp;
    out[OFF_EB + t] = epsB[t] + 0.5f * (t1 + t2v);
  }
  if (tid < Dd) {
    float m = accv(part, AIDX(40, t, 41 + tid)) / kap;
    mus[tid] = m;
    out[OFF_MU + tid * Tt + t] = m;
  }
  __syncthreads();
  if (tid < Dd * Dd) {
    int i = tid / Dd, j = tid % Dd;
    float S = accv(part, AIDX(41 + i, t, 41 + j));
    float v = (i == j ? 500.f : 0.f) + S - kap * mus[i] * mus[j];
    out[OFF_PSI + (i * Dd + j) * Tt + t] = v;
  }
}

extern "C" void kernel_launch(void* const* d_in, const int* in_sizes, int n_in,
                              void* d_out, int out_size, void* d_ws, size_t ws_size,
                              hipStream_t stream) {
  const float* Phi = (const float*)d_in[1];
  const float* Xd  = (const float*)d_in[2];
  const float* Yd  = (const float*)d_in[3];
  const float* W   = (const float*)d_in[4];
  const float* bb  = (const float*)d_in[5];
  const float* eA  = (const float*)d_in[6];
  const float* eB  = (const float*)d_in[7];
  const float* zA  = (const float*)d_in[8];
  const float* zB  = (const float*)d_in[9];
  float* out = (float*)d_out;
  float* ws  = (float*)d_ws;

  unsigned short* XeHi = (unsigned short*)(ws + XEH_OFF);
  unsigned short* XeLo = (unsigned short*)(ws + XEL_OFF);
  float* PhiT = ws + PHIT_OFF;
  float* part = ws + PART_OFF;
  float* P    = ws + P_OFF;

  // adapt chunk count to workspace (deterministic, graph-safe); target
  // grid ~= 241 blocks (one 8-wave block per CU, sp=13 K-steps each)
  long maxChunks = ((long)(ws_size / 4) - (long)P_OFF) / CSZ;
  if (maxChunks < 1) maxChunks = 1;
  long cap = maxChunks < 256 ? maxChunks : 256;
  long sp = (3125 + cap - 1) / cap;               // 32-k steps per chunk
  int CH = (int)(32 * sp);
  int KCe = (Nn + CH - 1) / CH;

  hipLaunchKernelGGL(elm_expand, dim3((Nn + 63) / 64), dim3(256), 0, stream,
                     Phi, Xd, Yd, W, bb, XeHi, XeLo, PhiT);
  hipLaunchKernelGGL(gram_mfma, dim3(KCe), dim3(512), 0, stream,
                     PhiT, XeHi, XeLo, P, CH);
  hipLaunchKernelGGL(reduce_a, dim3(52, 8), dim3(256), 0, stream,
                     (const float4*)P, KCe, (float4*)part);
  hipLaunchKernelGGL(finalize_kernel, dim3(Tt), dim3(256), 0, stream,
                     part, eA, eB, zA, zB, out);
}

// Round 5
// 170.485 us; speedup vs baseline: 1.2132x; 1.0007x over previous
//
#include <hip/hip_runtime.h>

#define Nn 100000
#define Tt 16
#define Dd 8
#define Hh 40
#define HP1 41

// ---- gram geometry (fixed) ----
#define SPC 13                 // 32-k steps per chunk
#define CH  (32 * SPC)         // 416 n per chunk
#define KCMAX ((Nn + CH - 1) / CH)    // 241 chunks

// ---- workspace layout (float slots) ----
#define CSZ 53248                      // 52*16*64 floats per chunk-partial
#define XEH_OFF  0                     // XeHi [64][Nn] f16 -> 32*Nn float slots
#define XEL_OFF  (XEH_OFF + 32 * Nn)   // XeLo [64][Nn] f16
#define PHIT_OFF (XEL_OFF + 32 * Nn)   // PhiT [16][Nn] f32
#define PART_OFF (PHIT_OFF + 16 * Nn)  // 8 * CSZ partials
#define P_OFF    (PART_OFF + 8 * CSZ)  // chunk partials

// output offsets (flat, return order)
#define OFF_BG1   0
#define OFF_BG2   16
#define OFF_MU    32
#define OFF_KAPPA 160
#define OFF_NU    176
#define OFF_PSI   192
#define OFF_WM    1216
#define OFF_WS    1872
#define OFF_ZA    28768
#define OFF_ZB    28784
#define OFF_EA    28800
#define OFF_EB    28816

typedef _Float16 f16x8 __attribute__((ext_vector_type(8)));
typedef float f32x4 __attribute__((ext_vector_type(4)));
typedef unsigned int u32x4 __attribute__((ext_vector_type(4)));

// A-index into partials: value A[t][i][j] at ((i*16+t)*64)+j
#define AIDX(i, t, j) ((((i) * 16 + (t)) * 64) + (j))

// ---------------- Kernel 0: ELM expansion -> XeHi/XeLo planes + PhiT ------
// Xe row layout c: [h0..h39, 1, x0..x7, y, 0...0] (c=50..63 zero)
__global__ __launch_bounds__(256)
void elm_expand(const float* __restrict__ Phi, const float* __restrict__ Xd,
                const float* __restrict__ Yd, const float* __restrict__ W,
                const float* __restrict__ bb,
                unsigned short* __restrict__ XeHi, unsigned short* __restrict__ XeLo,
                float* __restrict__ PhiT)
{
  __shared__ float sW[Dd * Hh];
  __shared__ float sb[Hh];
  __shared__ float xs[64][9];
  __shared__ float ys[64];
  __shared__ float hrow[64][41];
  __shared__ float pt[16][68];
  int tid = threadIdx.x;
  int n0 = blockIdx.x * 64;

  for (int i = tid; i < Dd * Hh; i += 256) sW[i] = W[i];
  if (tid < Hh) sb[tid] = bb[tid];
  if (tid < 128) {
    int nl = tid >> 1, h4 = (tid & 1) * 4;
    int gn = n0 + nl;
    float4 v = (gn < Nn) ? *(const float4*)(Xd + (size_t)gn * 8 + h4)
                         : make_float4(0.f, 0.f, 0.f, 0.f);
    xs[nl][h4 + 0] = v.x; xs[nl][h4 + 1] = v.y;
    xs[nl][h4 + 2] = v.z; xs[nl][h4 + 3] = v.w;
  }
  if (tid < 64) { int gn = n0 + tid; ys[tid] = (gn < Nn) ? Yd[gn] : 0.f; }
  {
    int nl = tid >> 2, q = tid & 3;
    int gn = n0 + nl;
    float4 v = (gn < Nn) ? *(const float4*)(Phi + (size_t)gn * 16 + q * 4)
                         : make_float4(0.f, 0.f, 0.f, 0.f);
    pt[q * 4 + 0][nl] = v.x; pt[q * 4 + 1][nl] = v.y;
    pt[q * 4 + 2][nl] = v.z; pt[q * 4 + 3][nl] = v.w;
  }
  __syncthreads();
  // sigmoids: thread -> (n, 10 h's)
  {
    int nl = tid >> 2, hq = (tid & 3) * 10;
    for (int hh = 0; hh < 10; ++hh) {
      int h = hq + hh;
      float z = sb[h];
#pragma unroll
      for (int d = 0; d < 8; ++d) z = fmaf(xs[nl][d], sW[d * Hh + h], z);
      hrow[nl][h] = 1.f / (1.f + __expf(-z));
    }
  }
  __syncthreads();
  // PhiT write: thread (t = tid&15, nq = tid>>4) -> float4
  {
    int t = tid & 15, nq = tid >> 4;
    int gn = n0 + nq * 4;
    if (gn < Nn) {
      float4 v = make_float4(pt[t][nq * 4 + 0], pt[t][nq * 4 + 1],
                             pt[t][nq * 4 + 2], pt[t][nq * 4 + 3]);
      *(float4*)(PhiT + (size_t)t * Nn + gn) = v;
    }
  }
  // Xe hi/lo planes: thread (c = tid>>2, seg = tid&3) covers 16 n's
  {
    int cidx = tid >> 2, seg = tid & 3;
    int nl0 = seg * 16;
    float vv[16];
#pragma unroll
    for (int j = 0; j < 16; ++j) {
      int n = nl0 + j;
      float v;
      if (cidx < Hh) v = hrow[n][cidx];
      else if (cidx == 40) v = 1.f;
      else if (cidx < 49) v = xs[n][cidx - 41];
      else if (cidx == 49) v = ys[n];
      else v = 0.f;
      vv[j] = v;
    }
    unsigned short hs[16], ls[16];
#pragma unroll
    for (int j = 0; j < 16; ++j) {
      _Float16 h = (_Float16)vv[j];
      float r = vv[j] - (float)h;
      _Float16 lo = (_Float16)r;
      hs[j] = __builtin_bit_cast(unsigned short, h);
      ls[j] = __builtin_bit_cast(unsigned short, lo);
    }
#pragma unroll
    for (int q2 = 0; q2 < 2; ++q2) {
      int gn = n0 + nl0 + q2 * 8;
      if (gn < Nn) {
        uint4 uh, ul;
        uh.x = hs[q2*8+0] | ((unsigned)hs[q2*8+1] << 16);
        uh.y = hs[q2*8+2] | ((unsigned)hs[q2*8+3] << 16);
        uh.z = hs[q2*8+4] | ((unsigned)hs[q2*8+5] << 16);
        uh.w = hs[q2*8+6] | ((unsigned)hs[q2*8+7] << 16);
        ul.x = ls[q2*8+0] | ((unsigned)ls[q2*8+1] << 16);
        ul.y = ls[q2*8+2] | ((unsigned)ls[q2*8+3] << 16);
        ul.z = ls[q2*8+4] | ((unsigned)ls[q2*8+5] << 16);
        ul.w = ls[q2*8+6] | ((unsigned)ls[q2*8+7] << 16);
        *(uint4*)(XeHi + (size_t)cidx * Nn + gn) = uh;
        *(uint4*)(XeLo + (size_t)cidx * Nn + gn) = ul;
      }
    }
  }
}

// ---------------- Kernel 1: MFMA Gram, 4-deep counted-vmcnt pipeline ----------------
// One block per K-chunk (grid-stride if ws-limited). 8 waves cover 52 i-rows.
// A rows are a SUBSET of B rows: staged B hi/lo planes serve both operands.
// LDS: 4 ring buffers x 8KB (Bhi[64][32k]f16 @0, Blo @4096), then static phi
// region [13 steps][16 t][32 k]f32 (26.6KB, staged once per chunk).
// Swizzles (source-preswizzled, linear LDS dest; same involution on ds_read):
//   B granule' = g ^ (row&3); phi granule' = g ^ (t&7).
// Pipeline: prologue stages phi + steps 0..2; loop s: s_waitcnt vmcnt(2|1|0),
// s_barrier (no drain -> stages s+1,s+2 stay in flight), STAGE(s+3), compute.
__device__ __forceinline__ void gload16(const void* g, void* l) {
  __builtin_amdgcn_global_load_lds(
      (const __attribute__((address_space(1))) unsigned int*)g,
      (__attribute__((address_space(3))) unsigned int*)l, 16, 0, 0);
}

#define PHI_LDS 32768            // byte offset of phi region
#define LDS_BYTES (PHI_LDS + 16 * CH * 4)   // 32768 + 26624 = 59392

__global__ __launch_bounds__(512, 2)
void gram_mfma(const float* __restrict__ PhiT,
               const unsigned short* __restrict__ XeHi,
               const unsigned short* __restrict__ XeLo,
               float* __restrict__ P)
{
  __shared__ __align__(16) char smem[LDS_BYTES];

  int tid = threadIdx.x;
  int l = tid & 63, w = tid >> 6;
  int l15 = l & 15, lg = l >> 4;

  // per-wave M-tile range: waves 0-3 own 7 tiles, 4-7 own 6 (total 52)
  int MT  = (w < 4) ? 7 : 6;
  int i0w = (w < 4) ? 7 * w : 28 + 6 * (w - 4);

  // ---- static read offsets (bytes) ----
  int off_b[4];
#pragma unroll
  for (int nt = 0; nt < 4; ++nt) {
    int j = l15 + 16 * nt;
    off_b[nt] = j * 64 + 16 * (lg ^ (j & 3));
  }
  int off_a[7];
#pragma unroll
  for (int mi = 0; mi < 7; ++mi) {
    int i = i0w + mi;              // <= 52; rows >= 50 are exact zeros
    off_a[mi] = i * 64 + 16 * (lg ^ (i & 3));
  }
  int off_p0 = l15 * 128 + 16 * ((2 * lg) ^ (l15 & 7));
  int off_p1 = l15 * 128 + 16 * ((2 * lg + 1) ^ (l15 & 7));
  int ld0 = tid * 16;              // linear LDS stage dest (within buffer)
  int brow = (tid & 255) >> 2, bsl = tid & 3;   // B stage decode
  const unsigned short* bplane = (tid < 256) ? XeHi : XeLo;  // wave-uniform

  f32x4 acc[7][4];
#pragma unroll
  for (int mi = 0; mi < 7; ++mi)
#pragma unroll
    for (int nt = 0; nt < 4; ++nt) acc[mi][nt] = (f32x4){0.f, 0.f, 0.f, 0.f};

  for (int cc = blockIdx.x; cc < KCMAX; cc += gridDim.x) {
    int n0 = cc * CH;
    int rem = Nn - n0; if (rem > CH) rem = CH;
    int nsteps = rem >> 5;         // 13 (or 5 for the last chunk)

    // protect LDS reuse across segments (harmless on first)
    __builtin_amdgcn_s_barrier();
    asm volatile("" ::: "memory");

    // B stage source base for step 0 (advance 64B/step)
    const char* gB = (const char*)(bplane + (size_t)brow * Nn + n0
                                   + 8 * (bsl ^ (brow & 3)));
#define STAGE(sx) gload16(gB + (size_t)(sx) * 64, \
                          &smem[(((sx) & 3) * 8192) + ld0])

    // phi prologue: stage [SPC][16][32] f32, pre-swizzled source
#pragma unroll
    for (int q = 0; q < 4; ++q) {
      int gp = tid + q * 512;
      if (gp < 16 * CH / 4) {                       // 1664 granules
        int s = gp >> 7, qq = gp & 127, t = qq >> 3, sl = qq & 7;
        gload16(PhiT + (size_t)t * Nn + n0 + s * 32 + 4 * (sl ^ (t & 7)),
                &smem[PHI_LDS + gp * 16]);
      }
    }
    STAGE(0);
    if (nsteps > 1) STAGE(1);
    if (nsteps > 2) STAGE(2);

    for (int s = 0; s < nsteps; ++s) {
      // counted wait: stage s landed; stages s+1,s+2 stay in flight
      int out = nsteps - 1 - s; if (out > 2) out = 2;
      if (out == 2)      asm volatile("s_waitcnt vmcnt(2)" ::: "memory");
      else if (out == 1) asm volatile("s_waitcnt vmcnt(1)" ::: "memory");
      else               asm volatile("s_waitcnt vmcnt(0)" ::: "memory");
      __builtin_amdgcn_s_barrier();
      asm volatile("" ::: "memory");
      if (s + 3 < nsteps) STAGE(s + 3);

      const char* base  = &smem[(s & 3) * 8192];
      const char* pbase = &smem[PHI_LDS + s * 2048];
      f32x4 p0 = *(const f32x4*)(pbase + off_p0);
      f32x4 p1 = *(const f32x4*)(pbase + off_p1);
      float ph[8] = {p0[0], p0[1], p0[2], p0[3], p1[0], p1[1], p1[2], p1[3]};

      f16x8 bh[4], bl[4];
#pragma unroll
      for (int nt = 0; nt < 4; ++nt) {
        bh[nt] = *(const f16x8*)(base + off_b[nt]);
        bl[nt] = *(const f16x8*)(base + 4096 + off_b[nt]);
      }
      __builtin_amdgcn_s_setprio(1);
#pragma unroll
      for (int mi = 0; mi < 7; ++mi) {
        if (mi >= MT) break;
        f16x8 xh = *(const f16x8*)(base + off_a[mi]);          // broadcast
        f16x8 xl = *(const f16x8*)(base + 4096 + off_a[mi]);   // broadcast
        float v0 = ph[0] * ((float)xh[0] + (float)xl[0]);
        float v1 = ph[1] * ((float)xh[1] + (float)xl[1]);
        float v2 = ph[2] * ((float)xh[2] + (float)xl[2]);
        float v3 = ph[3] * ((float)xh[3] + (float)xl[3]);
        float v4 = ph[4] * ((float)xh[4] + (float)xl[4]);
        float v5 = ph[5] * ((float)xh[5] + (float)xl[5]);
        float v6 = ph[6] * ((float)xh[6] + (float)xl[6]);
        float v7 = ph[7] * ((float)xh[7] + (float)xl[7]);
        auto h0 = __builtin_amdgcn_cvt_pkrtz(v0, v1);
        auto h1 = __builtin_amdgcn_cvt_pkrtz(v2, v3);
        auto h2 = __builtin_amdgcn_cvt_pkrtz(v4, v5);
        auto h3 = __builtin_amdgcn_cvt_pkrtz(v6, v7);
        float r0 = v0 - (float)h0[0], r1 = v1 - (float)h0[1];
        float r2 = v2 - (float)h1[0], r3 = v3 - (float)h1[1];
        float r4 = v4 - (float)h2[0], r5 = v5 - (float)h2[1];
        float r6 = v6 - (float)h3[0], r7 = v7 - (float)h3[1];
        auto e0 = __builtin_amdgcn_cvt_pkrtz(r0, r1);
        auto e1 = __builtin_amdgcn_cvt_pkrtz(r2, r3);
        auto e2 = __builtin_amdgcn_cvt_pkrtz(r4, r5);
        auto e3 = __builtin_amdgcn_cvt_pkrtz(r6, r7);
        u32x4 uh = {__builtin_bit_cast(unsigned int, h0), __builtin_bit_cast(unsigned int, h1),
                    __builtin_bit_cast(unsigned int, h2), __builtin_bit_cast(unsigned int, h3)};
        u32x4 ul = {__builtin_bit_cast(unsigned int, e0), __builtin_bit_cast(unsigned int, e1),
                    __builtin_bit_cast(unsigned int, e2), __builtin_bit_cast(unsigned int, e3)};
        f16x8 ah = __builtin_bit_cast(f16x8, uh);
        f16x8 al = __builtin_bit_cast(f16x8, ul);
#pragma unroll
        for (int nt = 0; nt < 4; ++nt) {
          acc[mi][nt] = __builtin_amdgcn_mfma_f32_16x16x32_f16(ah, bh[nt], acc[mi][nt], 0, 0, 0);
          acc[mi][nt] = __builtin_amdgcn_mfma_f32_16x16x32_f16(ah, bl[nt], acc[mi][nt], 0, 0, 0);
          acc[mi][nt] = __builtin_amdgcn_mfma_f32_16x16x32_f16(al, bh[nt], acc[mi][nt], 0, 0, 0);
        }
      }
      __builtin_amdgcn_s_setprio(0);
    }
#undef STAGE
  }

  // epilogue: C row = t = lg*4+r, col = j (verified C map); slab = blockIdx.x
  float* Pc = P + (size_t)blockIdx.x * CSZ;
#pragma unroll
  for (int mi = 0; mi < 7; ++mi) {
    if (mi >= MT) break;
    int i = i0w + mi;
#pragma unroll
    for (int nt = 0; nt < 4; ++nt) {
      int j = nt * 16 + l15;
#pragma unroll
      for (int r = 0; r < 4; ++r)
        Pc[(i * 16 + lg * 4 + r) * 64 + j] = acc[mi][nt][r];
    }
  }
}

// ---------------- Kernel 2: slab reduction (nslabs -> 8 groups) ----------------
__global__ __launch_bounds__(256)
void reduce_a(const float4* __restrict__ P4, int nslabs, float4* __restrict__ part4)
{
  int g = blockIdx.y;                               // 0..7
  int idx = blockIdx.x * 256 + threadIdx.x;         // 52 blocks cover CSZ/4
  int per = (nslabs + 7) / 8;
  int c0 = g * per, c1 = c0 + per; if (c1 > nslabs) c1 = nslabs;
  float4 s = make_float4(0.f, 0.f, 0.f, 0.f);
  for (int cc = c0; cc < c1; ++cc) {
    float4 v = P4[(size_t)cc * (CSZ / 4) + idx];
    s.x += v.x; s.y += v.y; s.z += v.z; s.w += v.w;
  }
  part4[(size_t)g * (CSZ / 4) + idx] = s;
}

// ---------------- Kernel 3: finalize (GJ inverse etc.), sums 8 partials inline ------
__device__ __forceinline__ float accv(const float* __restrict__ part, int idx) {
  float s = 0.f;
#pragma unroll
  for (int g = 0; g < 8; ++g) s += part[g * CSZ + idx];
  return s;
}

__global__ __launch_bounds__(256)
void finalize_kernel(const float* __restrict__ part, const float* __restrict__ epsA,
                     const float* __restrict__ epsB, const float* __restrict__ zetA,
                     const float* __restrict__ zetB, float* __restrict__ out)
{
  int t = blockIdx.x;
  int tid = threadIdx.x;
  __shared__ float G[HP1][84];          // [M | I] augmented
  __shared__ float As[HP1][HP1 + 1];
  __shared__ float bs[HP1];
  __shared__ float colk[HP1];
  __shared__ float red[256];
  __shared__ float wmv[HP1];
  __shared__ float rowv[4][HP1 + 1];
  __shared__ float mus[Dd];

  float epsExp = epsA[t] / epsB[t];
  float zetaExp = zetA[t] / zetB[t];

  for (int idx = tid; idx < HP1 * HP1; idx += 256) {
    int i = idx / HP1, j = idx % HP1;
    float a = accv(part, AIDX(i, t, j));
    As[i][j] = a;
    G[i][j] = epsExp * a + (i == j ? zetaExp : 0.f);
    G[i][41 + j] = (i == j) ? 1.f : 0.f;
  }
  for (int idx = tid; idx < HP1; idx += 256) {
    G[idx][82] = 0.f; G[idx][83] = 0.f;
    bs[idx] = accv(part, AIDX(idx, t, 49));
  }
  __syncthreads();

  int c = tid % HP1;         // 0..40
  int ig = tid / HP1;        // 0..6; ig<6 active
  int irow0 = ig * 7;

  for (int k = 0; k < HP1; ++k) {
    float pivinv = 1.f / G[k][k];
    if (tid >= 1 && tid <= HP1) G[k][k + tid] *= pivinv;
    if (tid < HP1) colk[tid] = (tid == k) ? 0.f : G[tid][k];
    __syncthreads();
    if (ig < 6) {
      int j = k + 1 + c;
      float pk = G[k][j];
#pragma unroll
      for (int r = 0; r < 7; ++r) {
        int i = irow0 + r;
        if (i < HP1 && i != k) G[i][j] = fmaf(-colk[i], pk, G[i][j]);
      }
    }
    __syncthreads();
  }

  for (int idx = tid; idx < HP1 * HP1; idx += 256) {
    int i = idx / HP1, j = idx % HP1;
    out[OFF_WS + (t * HP1 + i) * HP1 + j] = G[i][41 + j];
  }
  if (tid < HP1) {
    float s = 0.f;
    for (int j = 0; j < HP1; ++j) s += G[tid][41 + j] * bs[j];
    float w = zetaExp * s;
    wmv[tid] = w;
    out[OFF_WM + t * HP1 + tid] = w;
  }
  __syncthreads();
  float lt2 = 0.f;
  for (int idx = tid; idx < HP1 * HP1; idx += 256) {
    int i = idx / HP1, j = idx % HP1;
    lt2 += As[i][j] * G[i][41 + j];
  }
  red[tid] = lt2; __syncthreads();
  for (int s = 128; s > 0; s >>= 1) {
    if (tid < s) red[tid] += red[tid + s];
    __syncthreads();
  }
  float t2v = red[0];
  if (tid < HP1) {
    float w = wmv[tid];
    float aw = 0.f;
    for (int j = 0; j < HP1; ++j) aw += As[tid][j] * wmv[j];
    rowv[0][tid] = w * bs[tid];
    rowv[1][tid] = w * w;
    rowv[2][tid] = G[tid][41 + tid];
    rowv[3][tid] = w * aw;
  }
  __syncthreads();

  float sp = accv(part, AIDX(40, t, 40));
  float kap = 1000.f + sp;
  float syy = accv(part, AIDX(49, t, 49));

  if (tid == 0) {
    float wb = 0.f, wn = 0.f, trc = 0.f, quad = 0.f;
    for (int i = 0; i < HP1; ++i) {
      wb += rowv[0][i]; wn += rowv[1][i]; trc += rowv[2][i]; quad += rowv[3][i];
    }
    float t1 = syy - 2.f * wb + quad;
    out[OFF_BG1 + t] = 1.f + sp;
    float rest = 0.f;
    for (int u = t + 1; u < Tt; ++u) rest += accv(part, AIDX(40, u, 40));
    out[OFF_BG2 + t] = 1.f + rest;            // ALPHA_DP = 1
    out[OFF_KAPPA + t] = kap;
    out[OFF_NU + t] = sp + 100.f;
    out[OFF_ZA + t] = zetA[t] + 0.5f * (float)HP1;
    out[OFF_ZB + t] = zetB[t] + 0.5f * (wn + trc);
    out[OFF_EA + t] = epsA[t] + 0.5f * sp;
    out[OFF_EB + t] = epsB[t] + 0.5f * (t1 + t2v);
  }
  if (tid < Dd) {
    float m = accv(part, AIDX(40, t, 41 + tid)) / kap;
    mus[tid] = m;
    out[OFF_MU + tid * Tt + t] = m;
  }
  __syncthreads();
  if (tid < Dd * Dd) {
    int i = tid / Dd, j = tid % Dd;
    float S = accv(part, AIDX(41 + i, t, 41 + j));
    float v = (i == j ? 500.f : 0.f) + S - kap * mus[i] * mus[j];
    out[OFF_PSI + (i * Dd + j) * Tt + t] = v;
  }
}

extern "C" void kernel_launch(void* const* d_in, const int* in_sizes, int n_in,
                              void* d_out, int out_size, void* d_ws, size_t ws_size,
                              hipStream_t stream) {
  const float* Phi = (const float*)d_in[1];
  const float* Xd  = (const float*)d_in[2];
  const float* Yd  = (const float*)d_in[3];
  const float* W   = (const float*)d_in[4];
  const float* bb  = (const float*)d_in[5];
  const float* eA  = (const float*)d_in[6];
  const float* eB  = (const float*)d_in[7];
  const float* zA  = (const float*)d_in[8];
  const float* zB  = (const float*)d_in[9];
  float* out = (float*)d_out;
  float* ws  = (float*)d_ws;

  unsigned short* XeHi = (unsigned short*)(ws + XEH_OFF);
  unsigned short* XeLo = (unsigned short*)(ws + XEL_OFF);
  float* PhiT = ws + PHIT_OFF;
  float* part = ws + PART_OFF;
  float* P    = ws + P_OFF;

  // slab count bounded by workspace (deterministic, graph-safe);
  // grid-stride in gram_mfma covers all KCMAX chunks regardless
  long maxSlabs = ((long)(ws_size / 4) - (long)P_OFF) / CSZ;
  int grid1 = (int)(maxSlabs < KCMAX ? maxSlabs : KCMAX);
  if (grid1 < 1) grid1 = 1;

  hipLaunchKernelGGL(elm_expand, dim3((Nn + 63) / 64), dim3(256), 0, stream,
                     Phi, Xd, Yd, W, bb, XeHi, XeLo, PhiT);
  hipLaunchKernelGGL(gram_mfma, dim3(grid1), dim3(512), 0, stream,
                     PhiT, XeHi, XeLo, P);
  hipLaunchKernelGGL(reduce_a, dim3(52, 8), dim3(256), 0, stream,
                     (const float4*)P, grid1, (float4*)part);
  hipLaunchKernelGGL(finalize_kernel, dim3(Tt), dim3(256), 0, stream,
                     part, eA, eB, zA, zB, out);
}